// Round 10
// baseline (11365.220 us; speedup 1.0000x reference)
//
#include <hip/hip_runtime.h>

typedef unsigned short u16;
typedef unsigned int u32;
typedef _Float16 f16;
typedef f16   f16x2 __attribute__((ext_vector_type(2)));
typedef f16   f16x4 __attribute__((ext_vector_type(4)));
typedef f16   f16x8 __attribute__((ext_vector_type(8)));
typedef float f32x4 __attribute__((ext_vector_type(4)));

#define MFMA16(a,b,c) __builtin_amdgcn_mfma_f32_16x16x32_f16((a),(b),(c),0,0,0)

__device__ __forceinline__ float sigm_(float x){ return 1.f/(1.f + __expf(-x)); }
__device__ __forceinline__ float tanh_(float x){ return 1.f - 2.f/(1.f + __expf(2.f*x)); }
__device__ __forceinline__ float clampf(float x, float c){
  if (!(x > -c)) x = -c;
  if (x > c) x = c;
  return x;
}
__device__ __forceinline__ f16x8 cvt8f(const float* p){
  const float4 a = *(const float4*)p;
  const float4 b = *(const float4*)(p+4);
  f16x8 r;
  r[0]=(f16)a.x; r[1]=(f16)a.y; r[2]=(f16)a.z; r[3]=(f16)a.w;
  r[4]=(f16)b.x; r[5]=(f16)b.y; r[6]=(f16)b.z; r[7]=(f16)b.w;
  return r;
}

// device-scope multi-block barrier (co-resident blocks; per-instance counter, zeroed per launch)
__device__ __forceinline__ void gbar_(u32* c, u32 nb){
  __syncthreads();
  __threadfence();
  if (threadIdx.x == 0) {
    __hip_atomic_fetch_add(c, 1u, __ATOMIC_RELAXED, __HIP_MEMORY_SCOPE_AGENT);
    while (__hip_atomic_load(c, __ATOMIC_RELAXED, __HIP_MEMORY_SCOPE_AGENT) < nb) {}
  }
  __syncthreads();
  __threadfence();
}

// ---------- diagnostic ----------
__global__ void k_diag(float* out, int mib){
  const int i = blockIdx.x*256 + threadIdx.x;
  if (i < 3072) out[i] = 1000.f * (float)mib;
}

// ---------- decoder weight swizzle (fp32 -> f16 MFMA B-frags) ----------
__global__ void k_prep_dec(const float* dWhh, const float* attnW, const float* fccon,
                           const float* dWih, f16* R3)
{
  long idx = (long)blockIdx.x*256 + threadIdx.x;
  const float* src; int rs, colOff = 0, NKS; long dst, loc;
  if (idx < 294912L) {
    loc = idx; const int m = (int)(loc / 98304); loc %= 98304;
    src = dWhh + (long)m*786432; rs = 512; NKS = 16; dst = (long)m*786432;
  } else if (idx < 327680L) {
    loc = idx - 294912L; src = attnW; colOff = 512; rs = 1024; NKS = 16; dst = 2359296L;
  } else if (idx < 393216L) {
    loc = idx - 327680L; src = fccon; rs = 1024; NKS = 32; dst = 2621440L;
  } else if (idx < 688128L) {
    loc = idx - 393216L; const int m = (int)(loc / 98304); loc %= 98304;
    src = dWih + (long)m*786432; rs = 512; NKS = 16; dst = 3440640L + (long)m*786432;
  } else if (idx < 720896L) {
    loc = idx - 688128L; src = attnW; colOff = 0; rs = 1024; NKS = 16; dst = 5799936L;
  } else return;
  const int lane = (int)(loc & 63);
  const long frag = loc >> 6;
  const int ks = (int)(frag % NKS);
  const long nt = frag / NKS;
  const int n  = (int)(nt*16 + (lane & 15));
  const int k0 = ks*32 + ((lane >> 4) << 3);
  const float* sp = src + (long)n*rs + colOff + k0;
  f16* dp = R3 + dst + loc*8;
  #pragma unroll
  for (int j = 0; j < 8; ++j) dp[j] = (f16)sp[j];
}

// ---------- layer-0 gi, v2 layout: per-thread-contiguous 24 f16 ----------
__global__ void k_gi0s(const float* __restrict__ x, const float* __restrict__ W,
                       const float* __restrict__ bi, f16* __restrict__ gi,
                       int seg, int BH, int lbh, int b0)
{
  const long idx = (long)blockIdx.x*256 + threadIdx.x;
  const int v = (int)(idx % 24);
  long rest = idx / 24;
  const int tid = (int)(rest & 511); rest >>= 9;
  const int bq = (int)(rest & ((1 << (lbh-4)) - 1)); rest >>= (lbh-4);
  const int s = (int)(rest & 63);
  const int d = (int)(rest >> 6);
  const int r = v / 6, rem = v % 6, i = rem / 3, g = rem % 3;
  const int w = tid >> 6, q = (tid >> 4) & 3, lo = tid & 15;
  const int n = g*256 + (2*w + i)*16 + lo;
  const int b = bq*16 + q*4 + r;
  const int t = d ? (255 - (seg*64 + s)) : (seg*64 + s);
  const float x0 = x[(((b0+b)<<8) + t)*2];
  const float x1 = x[(((b0+b)<<8) + t)*2 + 1];
  const long wi = ((long)d*768 + n)*2;
  gi[idx] = (f16)clampf(x0*W[wi] + x1*W[wi+1] + bi[d*768 + n], 32.f);
}

// gi element accessor: 24 contiguous f16 held as 3 x f16x8
#define GIE(G, vv) ((float)((vv) < 8 ? (G)[0][(vv)&7] : ((vv) < 16 ? (G)[1][(vv)-8] : (G)[2][(vv)-16])))

// ---------- encoder recurrence: 512 thr / 8 waves (round-3/6/8/9 proven version) ----------
__global__ __launch_bounds__(512, 1) void k_enc_seg(
    const f16* __restrict__ gi, const float* __restrict__ Wraw,
    const float* __restrict__ bhh, f16* __restrict__ seq, int ostr,
    f16* __restrict__ fin, float* __restrict__ hcar, int seg, int BH)
{
  const int tid = threadIdx.x;
  const int w = tid >> 6, lane = tid & 63;
  const int lo16 = lane & 15, quad = lane >> 4;
  const int nbq = BH >> 4;
  const int dir = blockIdx.x / nbq, bq = blockIdx.x % nbq;

  __shared__ f16 h16[4][16][264];   // 4-deep ring: read s&3, write (s+1)&3, flush (s-1)&3

  const float* mat = Wraw + (long)dir*196608;   // [768][256] fp32
  f16x8 wr[6][8];
  #pragma unroll
  for (int p = 0; p < 3; ++p)
    #pragma unroll
    for (int i = 0; i < 2; ++i) {
      const int n = (p*16 + 2*w + i)*16 + lo16;
      #pragma unroll
      for (int ks = 0; ks < 8; ++ks)
        wr[p*2+i][ks] = cvt8f(mat + (long)n*256 + ks*32 + quad*8);
    }
  float bh_[3][2];
  #pragma unroll
  for (int p = 0; p < 3; ++p)
    #pragma unroll
    for (int i = 0; i < 2; ++i)
      bh_[p][i] = bhh[dir*768 + p*256 + (2*w+i)*16 + lo16];

  float hreg[2][4];
  if (seg == 0) {
    #pragma unroll
    for (int i = 0; i < 2; ++i)
      #pragma unroll
      for (int r = 0; r < 4; ++r) {
        hreg[i][r] = 0.f;
        h16[0][quad*4 + r][(2*w+i)*16 + lo16] = (f16)0.f;
      }
  } else {
    #pragma unroll
    for (int i = 0; i < 2; ++i) {
      const int c = (2*w+i)*16 + lo16;
      #pragma unroll
      for (int r = 0; r < 4; ++r) {
        const float v = hcar[((dir*BH) + bq*16 + quad*4 + r)*256 + c];
        hreg[i][r] = v;
        h16[0][quad*4 + r][c] = (f16)v;
      }
    }
  }

  const long gstep = (long)nbq*512*24;
  const f16* gbase = gi + (((long)dir*64*nbq + bq)*512 + tid)*24;
  f16x8 g0[3], g1[3];
  { const f16x8* gp = (const f16x8*)gbase; g0[0]=gp[0]; g0[1]=gp[1]; g0[2]=gp[2]; }

  const int frow = tid >> 5;        // flush mapping: 512 thr -> 16 rows x 32 col8
  const int fcol = (tid & 31) * 8;

  for (int s = 0; s < 64; ++s) {
    __syncthreads();                // h16[(s&3)] (written prev iter) visible
    if (s >= 2) {
      const int so = s - 2;
      const int t2 = dir ? (255 - (seg*64 + so)) : (seg*64 + so);
      const f16x8 hv = *(const f16x8*)&h16[(so+1)&3][frow][fcol];
      *(f16x8*)&seq[((long)t2*ostr + bq*16 + frow)*512 + dir*256 + fcol] = hv;
    }
    f32x4 acc[6];
    #pragma unroll
    for (int q = 0; q < 6; ++q) acc[q] = (f32x4){0.f,0.f,0.f,0.f};
    #pragma unroll
    for (int ks = 0; ks < 8; ++ks) {
      const f16x8 a = *(const f16x8*)&h16[s&3][lo16][ks*32 + quad*8];
      #pragma unroll
      for (int q = 0; q < 6; ++q)
        acc[q] = MFMA16(a, wr[q][ks], acc[q]);
    }
    if (s < 63) {
      const f16x8* gp = (const f16x8*)(gbase + (long)(s+1)*gstep);
      g1[0]=gp[0]; g1[1]=gp[1]; g1[2]=gp[2];
    }
    #pragma unroll
    for (int i = 0; i < 2; ++i) {
      const int c = (2*w+i)*16 + lo16;
      #pragma unroll
      for (int r = 0; r < 4; ++r) {
        const int row = quad*4 + r;
        const int v = r*6 + i*3;
        const float gir = GIE(g0, v);
        const float giz = GIE(g0, v+1);
        const float gin = GIE(g0, v+2);
        const float rv = sigm_(gir + acc[i][r]   + bh_[0][i]);
        const float zv = sigm_(giz + acc[2+i][r] + bh_[1][i]);
        const float nv = tanh_(gin + rv*(acc[4+i][r] + bh_[2][i]));
        float hn = (1.f - zv)*nv + zv*hreg[i][r];
        hn = clampf(hn, 2.f);
        hreg[i][r] = hn;
        h16[(s+1)&3][row][c] = (f16)hn;
        if (seg == 3 && s == 63) fin[(bq*16 + row)*512 + dir*256 + c] = (f16)hn;
      }
    }
    g0[0]=g1[0]; g0[1]=g1[1]; g0[2]=g1[2];
  }
  __syncthreads();
  #pragma unroll
  for (int so = 62; so < 64; ++so) {
    const int t2 = dir ? (255 - (seg*64 + so)) : (seg*64 + so);
    const f16x8 hv = *(const f16x8*)&h16[(so+1)&3][frow][fcol];
    *(f16x8*)&seq[((long)t2*ostr + bq*16 + frow)*512 + dir*256 + fcol] = hv;
  }
  #pragma unroll
  for (int i = 0; i < 2; ++i) {
    const int c = (2*w+i)*16 + lo16;
    #pragma unroll
    for (int r = 0; r < 4; ++r)
      hcar[((dir*BH) + bq*16 + quad*4 + r)*256 + c] = hreg[i][r];
  }
}

// ---------- big-path gi GEMM, j-quarter split: grid (64,4,2), acc[12] (round-8 proven) ----------
__global__ void k_gemm_gi(const f16* __restrict__ A,
                          const float* __restrict__ Braw, long bzs,
                          const float* __restrict__ bias,
                          f16* __restrict__ gi,
                          int tb0, int tb1, int tdirsgn, int abstr, float cv)
{
  const int tid = threadIdx.x, w = tid>>6, lane = tid&63;
  const int lo16 = lane&15, quad = lane>>4;
  const int s_ = blockIdx.x;
  const int y  = blockIdx.y;          // j-quarter 0..3
  const int z  = blockIdx.z;
  const int tbase = z ? tb1 : tb0;
  const int tdir  = z ? -tdirsgn : tdirsgn;
  const int mrow = s_*64 + w*16 + lo16;
  const long arow = (long)(tbase + tdir*(mrow >> 6))*abstr + (mrow & 63);
  const f16* Ap = A + arow*512 + quad*8;
  const float* Bp = Braw + (long)z*bzs;
  f32x4 acc[12];
  #pragma unroll
  for (int i=0;i<12;++i) acc[i]=(f32x4){0.f,0.f,0.f,0.f};
  for (int ks = 0; ks < 16; ++ks) {
    const f16x8 a = *(const f16x8*)(Ap + ks*32);
    #pragma unroll
    for (int g = 0; g < 3; ++g)
      #pragma unroll
      for (int jj = 0; jj < 4; ++jj) {
        const int n = g*256 + y*64 + jj*16 + lo16;
        const f16x8 b = cvt8f(Bp + (long)n*512 + ks*32 + quad*8);
        acc[g*4+jj] = MFMA16(a, b, acc[g*4+jj]);
      }
  }
  f16* base = gi + (((long)z*64 + s_)*4 + w)*12288L;
  #pragma unroll
  for (int l = 0; l < 2; ++l) {       // consumer w_c = y*2 + l ; jj = l*2 + jl
    f16x8 rec8[3];
    #pragma unroll
    for (int r = 0; r < 4; ++r)
      #pragma unroll
      for (int jl = 0; jl < 2; ++jl)
        #pragma unroll
        for (int g = 0; g < 3; ++g) {
          const int nt = g*4 + l*2 + jl;
          const int n = g*256 + y*64 + (l*2+jl)*16 + lo16;
          const int slot = r*6 + jl*3 + g;
          rec8[slot>>3][slot&7] = (f16)clampf(acc[nt][r] + bias[z*768 + n], cv);
        }
    f16* dp = base + ((long)(y*2 + l)*64 + quad*16 + lo16)*24L;
    *(f16x8*)(dp)      = rec8[0];
    *(f16x8*)(dp + 8)  = rec8[1];
    *(f16x8*)(dp + 16) = rec8[2];
  }
}

// ---------- MFMA GEMM; mode 0=f32 C, 1=f16 C, 2=f16 C gi-v2, 3=f16 C [b][t] transposed ----------
__global__ void k_gemm(const f16* __restrict__ A, int K,
                       const f16* __restrict__ Bsw, const float* __restrict__ Braw,
                       long bzs, int ldb, int koff,
                       const float* __restrict__ bias, int biaszs,
                       void* __restrict__ Cv, long czs, int ldc, int mode,
                       int tb0, int tb1, int tdirsgn, int lbh, int abstr, float cv)
{
  const int tid = threadIdx.x, w = tid>>6, lane = tid&63;
  const int lo16 = lane&15, quad = lane>>4;
  const int m0 = blockIdx.x*64 + w*16;
  const int n0 = blockIdx.y*128;
  const int z  = blockIdx.z;
  const int tbase = z ? tb1 : tb0;
  const int tdir  = z ? -tdirsgn : tdirsgn;
  const int NKS = K >> 5;
  const int mrow = m0 + lo16;
  const long arow = (long)(tbase + tdir*(mrow >> lbh))*abstr + (mrow & ((1<<lbh)-1));
  const f16* Ap = A + arow*K + quad*8;
  f32x4 acc[8];
  #pragma unroll
  for (int i=0;i<8;++i) acc[i]=(f32x4){0.f,0.f,0.f,0.f};
  if (Bsw) {
    const f16* Bp = Bsw + (long)z*bzs;
    for (int ks = 0; ks < NKS; ++ks) {
      const f16x8 a = *(const f16x8*)(Ap + ks*32);
      #pragma unroll
      for (int nt = 0; nt < 8; ++nt) {
        const f16x8 b = *(const f16x8*)(Bp + (((long)((n0>>4)+nt)*NKS + ks) << 9) + lane*8);
        acc[nt] = MFMA16(a, b, acc[nt]);
      }
    }
  } else {
    const float* Bp = Braw + (long)z*bzs;
    for (int ks = 0; ks < NKS; ++ks) {
      const f16x8 a = *(const f16x8*)(Ap + ks*32);
      #pragma unroll
      for (int nt = 0; nt < 8; ++nt) {
        const f16x8 b = cvt8f(Bp + (long)(n0 + nt*16 + lo16)*ldb + koff + ks*32 + quad*8);
        acc[nt] = MFMA16(a, b, acc[nt]);
      }
    }
  }
  #pragma unroll
  for (int nt = 0; nt < 8; ++nt) {
    const int n = n0 + nt*16 + lo16;
    const float bv = bias ? bias[z*biaszs + n] : 0.f;
    #pragma unroll
    for (int r = 0; r < 4; ++r) {
      const int m = m0 + quad*4 + r;
      const float val = clampf(acc[nt][r] + bv, cv);
      if (mode == 2) {
        const int s_ = m >> lbh, b_ = m & ((1<<lbh)-1);
        const int bq_ = b_ >> 4, q_ = (b_ >> 2) & 3, r_ = b_ & 3;
        const int g_ = n >> 8, j_ = (n >> 4) & 15, lo_ = n & 15;
        const long idx = ((((long)z*64 + s_)*(1<<(lbh-4)) + bq_)*512
                          + ((j_>>1)*64 + q_*16 + lo_))*24 + r_*6 + (j_&1)*3 + g_;
        ((f16*)Cv)[idx] = (f16)val;
      } else if (mode == 3)
        ((f16*)Cv)[(((long)(m & 63) << 8) + (m >> 6))*512 + n] = (f16)val;
      else if (mode == 1)
        ((f16*)Cv)[(long)z*czs + (long)m*ldc + n] = (f16)val;
      else
        ((float*)Cv)[(long)z*czs + (long)m*ldc + n] = val;
    }
  }
}

// ---------- (half path only) fused proj+score ----------
__global__ void k_score(const f16* __restrict__ seq, const f16* __restrict__ We,
                        const float* __restrict__ hq, const float* __restrict__ ab,
                        const float* __restrict__ vp, float* __restrict__ S)
{
  const int t = blockIdx.x, tid = threadIdx.x;
  const int w = tid>>6, lane = tid&63, lo16 = lane&15, quad = lane>>4;
  __shared__ float svab[1024];
  for (int i = tid; i < 512; i += 256) { svab[i] = vp[i]; svab[512+i] = ab[i]; }
  __syncthreads();
  f32x4 acc[32];
  #pragma unroll
  for (int i=0;i<32;++i) acc[i]=(f32x4){0.f,0.f,0.f,0.f};
  const f16* Ap = seq + ((long)t*64 + w*16 + lo16)*512 + quad*8;
  for (int ks = 0; ks < 16; ++ks) {
    const f16x8 a = *(const f16x8*)(Ap + ks*32);
    #pragma unroll
    for (int nt = 0; nt < 32; ++nt) {
      const f16x8 b = *(const f16x8*)(We + (((long)nt*16 + ks) << 9) + lane*8);
      acc[nt] = MFMA16(a, b, acc[nt]);
    }
  }
  #pragma unroll
  for (int r = 0; r < 4; ++r) {
    const int b = w*16 + quad*4 + r;
    float sc = 0.f;
    #pragma unroll
    for (int nt = 0; nt < 32; ++nt) {
      const int n = nt*16 + lo16;
      sc += svab[n] * tanh_(acc[nt][r] + hq[(b<<9) + n] + svab[512+n]);
    }
    sc += __shfl_xor(sc, 1, 64); sc += __shfl_xor(sc, 2, 64);
    sc += __shfl_xor(sc, 4, 64); sc += __shfl_xor(sc, 8, 64);
    if (lo16 == 0) S[(b<<8) + t] = clampf(sc, 256.f);
  }
}

// ---------- (half path only) softmax + context ----------
__global__ void k_attnctx(const float* __restrict__ S, const f16* __restrict__ enc,
                          f16* __restrict__ cat)
{
  const int b = blockIdx.x, tid = threadIdx.x;
  __shared__ float ssc[256], srd[256];
  const float sc = clampf(S[(b<<8) + tid], 256.f);
  srd[tid] = sc; __syncthreads();
  for (int off = 128; off > 0; off >>= 1) { if (tid < off) srd[tid] = fmaxf(srd[tid], srd[tid+off]); __syncthreads(); }
  const float mx = srd[0]; __syncthreads();
  const float e = __expf(sc - mx);
  srd[tid] = e; __syncthreads();
  for (int off = 128; off > 0; off >>= 1) { if (tid < off) srd[tid] += srd[tid+off]; __syncthreads(); }
  const float inv = 1.f / srd[0]; __syncthreads();
  ssc[tid] = e * inv; __syncthreads();
  float c0 = 0.f, c1 = 0.f;
  for (int tt = 0; tt < 256; ++tt) {
    const float awt = ssc[tt];
    const f16* ep = enc + (((long)tt*64 + b) << 9);
    c0 += awt * (float)ep[tid];
    c1 += awt * (float)ep[256 + tid];
  }
  cat[(b<<10) + 512 + tid] = (f16)clampf(c0, 4.f);
  cat[(b<<10) + 768 + tid] = (f16)clampf(c1, 4.f);
}

// ---------- decoder init (also zeroes barrier counters) ----------
__global__ void k_dec_init(const f16* __restrict__ fin, const f16* __restrict__ seq,
                           f16* __restrict__ hb16, float* __restrict__ hf32,
                           f16* __restrict__ cat, u32* __restrict__ cnt)
{
  const int idx = blockIdx.x*256 + threadIdx.x;
  if (idx < 128) cnt[idx] = 0;
  const int d = idx & 511, b = (idx >> 9) & 63, l = idx >> 15;
  if (l < 3) {
    const float v = clampf((float)fin[((long)l<<15) + (b<<9) + d], 2.f);
    hb16[(long)l*65536 + (b<<9) + d] = (f16)v;
    hf32[(long)l*32768 + (b<<9) + d] = v;
  } else {
    cat[(b<<10) + d] = seq[((long)255*64 + b)*512 + d];
  }
}

// ---------- persistent decoder (big path): all 24 steps in one kernel ----------
// 64 blocks x 512 thr. Per step: attn phase (block b = batch b), grid barrier,
// then 3 GRU layers (2 waves/block = 128 wave-jobs), grid barrier after each.
// All barriers are full-participation gbar_ with unique counters (24*4 = 96).
__global__ __launch_bounds__(512, 1) void k_dec_loop(
    const f16* __restrict__ seq, const f16* __restrict__ ep,
    f16* __restrict__ cat,
    const f16* __restrict__ whsw, const f16* __restrict__ fcsw,
    const float* __restrict__ fcconB, const float* __restrict__ vp,
    f16* __restrict__ inp, const float* __restrict__ fcW,
    const float* __restrict__ fcb, float* __restrict__ out,
    const f16* __restrict__ WihSw, const f16* __restrict__ WhhSw,
    const float* __restrict__ bihA, const float* __restrict__ bhhA,
    float* __restrict__ hfA, f16* __restrict__ hb, u32* __restrict__ cnt)
{
  const int b = blockIdx.x;
  const int tid = threadIdx.x, w = tid >> 6, lane = tid & 63;
  const int lo16 = lane & 15, quad = lane >> 4;
  __shared__ float hsm[512];
  __shared__ float cats[1024];
  __shared__ float hqs[512];
  __shared__ float aw[256];
  __shared__ float red[8*512];
  const float* hf2 = hfA + 2*32768;

  for (int s = 0; s < 24; ++s) {
    const int p = s & 1;
    // ================= attention phase =================
    hsm[tid]  = hf2[(b<<9) + tid];
    cats[tid] = (float)cat[(b<<10) + tid];
    __syncthreads();
    // output projection for previous step
    if (w < 2 && s > 0) {
      float pr = 0.f;
      #pragma unroll
      for (int j = 0; j < 8; ++j) pr += fcW[(w<<9) + lane*8 + j] * hsm[lane*8 + j];
      pr += __shfl_xor(pr,1,64); pr += __shfl_xor(pr,2,64); pr += __shfl_xor(pr,4,64);
      pr += __shfl_xor(pr,8,64); pr += __shfl_xor(pr,16,64); pr += __shfl_xor(pr,32,64);
      if (lane == 0) out[(b*24 + s-1)*2 + w] = clampf(pr + fcb[w], 128.f);
    }
    // hq = h_top @ Wh^T
    #pragma unroll
    for (int i = 0; i < 4; ++i) {
      const int nt = w*4 + i;
      float pr = 0.f;
      for (int ks = 0; ks < 16; ++ks) {
        const f16x8 wv = *(const f16x8*)(whsw + (((long)nt*16 + ks)<<9) + lane*8);
        const float4 ha = *(const float4*)&hsm[ks*32 + quad*8];
        const float4 hbv = *(const float4*)&hsm[ks*32 + quad*8 + 4];
        pr += (float)wv[0]*ha.x + (float)wv[1]*ha.y + (float)wv[2]*ha.z + (float)wv[3]*ha.w
            + (float)wv[4]*hbv.x + (float)wv[5]*hbv.y + (float)wv[6]*hbv.z + (float)wv[7]*hbv.w;
      }
      pr += __shfl_xor(pr,16,64); pr += __shfl_xor(pr,32,64);
      if (lane < 16) hqs[nt*16 + lane] = pr;
    }
    __syncthreads();
    // scores (ep in [b][t][512] layout)
    float hq8[8], v8[8];
    #pragma unroll
    for (int j = 0; j < 8; ++j) { hq8[j] = hqs[lane*8+j]; v8[j] = vp[lane*8+j]; }
    #pragma unroll 2
    for (int i = 0; i < 32; ++i) {
      const int t = w*32 + i;
      const f16x8 e = *(const f16x8*)(ep + (((long)(b<<8) + t)<<9) + lane*8);
      float sc = 0.f;
      #pragma unroll
      for (int j = 0; j < 8; ++j) sc += v8[j]*tanh_((float)e[j] + hq8[j]);
      sc += __shfl_xor(sc,1,64); sc += __shfl_xor(sc,2,64); sc += __shfl_xor(sc,4,64);
      sc += __shfl_xor(sc,8,64); sc += __shfl_xor(sc,16,64); sc += __shfl_xor(sc,32,64);
      if (lane == 0) aw[t] = clampf(sc, 256.f);
    }
    __syncthreads();
    // softmax over 256 (wave 0)
    if (tid < 64) {
      float s0=aw[tid], s1=aw[tid+64], s2=aw[tid+128], s3=aw[tid+192];
      float mx = fmaxf(fmaxf(s0,s1), fmaxf(s2,s3));
      mx = fmaxf(mx, __shfl_xor(mx,1,64)); mx = fmaxf(mx, __shfl_xor(mx,2,64));
      mx = fmaxf(mx, __shfl_xor(mx,4,64)); mx = fmaxf(mx, __shfl_xor(mx,8,64));
      mx = fmaxf(mx, __shfl_xor(mx,16,64)); mx = fmaxf(mx, __shfl_xor(mx,32,64));
      const float e0=__expf(s0-mx), e1=__expf(s1-mx), e2=__expf(s2-mx), e3=__expf(s3-mx);
      float sm = e0+e1+e2+e3;
      sm += __shfl_xor(sm,1,64); sm += __shfl_xor(sm,2,64); sm += __shfl_xor(sm,4,64);
      sm += __shfl_xor(sm,8,64); sm += __shfl_xor(sm,16,64); sm += __shfl_xor(sm,32,64);
      const float inv = 1.f/sm;
      aw[tid]=e0*inv; aw[tid+64]=e1*inv; aw[tid+128]=e2*inv; aw[tid+192]=e3*inv;
    }
    __syncthreads();
    // ctx = sum_t aw[t] * enc[t,b,:]
    float c8[8];
    #pragma unroll
    for (int j = 0; j < 8; ++j) c8[j] = 0.f;
    #pragma unroll 2
    for (int i = 0; i < 32; ++i) {
      const int t = w*32 + i;
      const f16x8 e = *(const f16x8*)(seq + (((long)t*64 + b)<<9) + lane*8);
      const float awt = aw[t];
      #pragma unroll
      for (int j = 0; j < 8; ++j) c8[j] += awt*(float)e[j];
    }
    #pragma unroll
    for (int j = 0; j < 8; ++j) red[(w<<9) + lane*8 + j] = c8[j];
    __syncthreads();
    {
      float sm = 0.f;
      #pragma unroll
      for (int ww = 0; ww < 8; ++ww) sm += red[(ww<<9) + tid];
      cats[512 + tid] = clampf(sm, 4.f);
    }
    __syncthreads();
    // inp = cat([d_in, ctx]) @ fc_con_W^T + b
    #pragma unroll
    for (int i = 0; i < 4; ++i) {
      const int nt = w*4 + i;
      float pr = 0.f;
      for (int ks = 0; ks < 32; ++ks) {
        const f16x8 wv = *(const f16x8*)(fcsw + (((long)nt*32 + ks)<<9) + lane*8);
        const float4 ca = *(const float4*)&cats[ks*32 + quad*8];
        const float4 cb = *(const float4*)&cats[ks*32 + quad*8 + 4];
        pr += (float)wv[0]*ca.x + (float)wv[1]*ca.y + (float)wv[2]*ca.z + (float)wv[3]*ca.w
            + (float)wv[4]*cb.x + (float)wv[5]*cb.y + (float)wv[6]*cb.z + (float)wv[7]*cb.w;
      }
      pr += __shfl_xor(pr,16,64); pr += __shfl_xor(pr,32,64);
      if (lane < 16) inp[(b<<9) + nt*16 + lane] = (f16)clampf(pr + fcconB[nt*16+lane], 64.f);
    }
    gbar_(cnt + s*4, 64);
    // ================= 3 GRU layers =================
    for (int l = 0; l < 3; ++l) {
      if (w < 2) {
        const int jid = (b<<1) + w;       // 0..127
        const int Wt = jid & 31, mi = jid >> 5;
        const f16* inl = (l == 0) ? inp : (hb + (long)(2*(l-1) + (1-p))*32768);
        const f16* WihL = WihSw + (long)l*786432;
        const f16* WhhL = WhhSw + (long)l*786432;
        const float* bih = bihA + l*1536;
        const float* bhh = bhhA + l*1536;
        float* hf32 = hfA + (long)l*32768;
        const f16* hin = hb + (long)(2*l + p)*32768;
        f16* hout = hb + (long)(2*l + (1-p))*32768;
        f16* catp = (l == 2) ? cat : (f16*)nullptr;

        f32x4 arz[2], an_[2];
        #pragma unroll
        for (int i=0;i<2;++i){ arz[i]=(f32x4){0.f,0.f,0.f,0.f}; an_[i]=(f32x4){0.f,0.f,0.f,0.f}; }
        #pragma unroll 4
        for (int kk = 0; kk < 16; ++kk) {               // gi part
          const f16x8 b0 = *(const f16x8*)(WihL + (((long)Wt*16 + kk)<<9)      + lane*8);
          const f16x8 b1 = *(const f16x8*)(WihL + (((long)(32+Wt)*16 + kk)<<9) + lane*8);
          const f16x8 b2 = *(const f16x8*)(WihL + (((long)(64+Wt)*16 + kk)<<9) + lane*8);
          const f16x8 a = *(const f16x8*)&inl[((mi*16 + lo16)<<9) + kk*32 + quad*8];
          arz[0] = MFMA16(a, b0, arz[0]);
          arz[1] = MFMA16(a, b1, arz[1]);
          an_[0] = MFMA16(a, b2, an_[0]);
        }
        #pragma unroll 4
        for (int kk = 0; kk < 16; ++kk) {               // gh part
          const f16x8 b0 = *(const f16x8*)(WhhL + (((long)Wt*16 + kk)<<9)      + lane*8);
          const f16x8 b1 = *(const f16x8*)(WhhL + (((long)(32+Wt)*16 + kk)<<9) + lane*8);
          const f16x8 b2 = *(const f16x8*)(WhhL + (((long)(64+Wt)*16 + kk)<<9) + lane*8);
          const f16x8 a = *(const f16x8*)&hin[((mi*16 + lo16)<<9) + kk*32 + quad*8];
          arz[0] = MFMA16(a, b0, arz[0]);
          arz[1] = MFMA16(a, b1, arz[1]);
          an_[1] = MFMA16(a, b2, an_[1]);
        }
        const int c = Wt*16 + lo16;
        const float brz0 = bih[c]     + bhh[c];
        const float brz1 = bih[512+c] + bhh[512+c];
        const float bin_ = bih[1024+c];
        const float bhn_ = bhh[1024+c];
        #pragma unroll
        for (int r = 0; r < 4; ++r) {
          const int row = mi*16 + quad*4 + r;
          const float rv = sigm_(clampf(arz[0][r],64.f) + brz0);
          const float zv = sigm_(clampf(arz[1][r],64.f) + brz1);
          const float nv = tanh_(clampf(an_[0][r],64.f) + bin_ + rv*(clampf(an_[1][r],64.f) + bhn_));
          const float ho = hf32[(row<<9) + c];
          float hn2 = (1.f - zv)*nv + zv*ho;
          hn2 = clampf(hn2, 2.f);
          hf32[(row<<9) + c] = hn2;
          hout[(row<<9) + c] = (f16)hn2;
          if (catp) catp[(row<<10) + c] = (f16)hn2;
        }
      }
      gbar_(cnt + s*4 + 1 + l, 64);
    }
  }
}

// ---------- (half path only) original raw-Wih cell ----------
__global__ void k_cell_raw(const f16* __restrict__ inp, const float* __restrict__ WihRaw,
                           const f16* __restrict__ WhhSw, const float* __restrict__ bih,
                           const float* __restrict__ bhh, float* __restrict__ hf32,
                           const f16* __restrict__ hin, f16* __restrict__ hout,
                           f16* __restrict__ cat)
{
  const int tid = threadIdx.x, w = tid>>6, lane = tid&63;
  const int lo16 = lane&15, quad = lane>>4;
  const int Wt = blockIdx.x*4 + w;
  f32x4 arz[8], an_[8];
  #pragma unroll
  for (int i=0;i<8;++i){ arz[i]=(f32x4){0.f,0.f,0.f,0.f}; an_[i]=(f32x4){0.f,0.f,0.f,0.f}; }
  const int nr = Wt*16 + lo16;
  const float* Rr = WihRaw + (long)nr*512        + quad*8;
  const float* Rz = WihRaw + (long)(512+nr)*512  + quad*8;
  const float* Rn = WihRaw + (long)(1024+nr)*512 + quad*8;
  #pragma unroll 2
  for (int kk = 0; kk < 16; ++kk) {
    const f16x8 b0 = cvt8f(Rr + kk*32);
    const f16x8 b1 = cvt8f(Rz + kk*32);
    const f16x8 b2 = cvt8f(Rn + kk*32);
    #pragma unroll
    for (int mi = 0; mi < 4; ++mi) {
      const f16x8 a = *(const f16x8*)&inp[((mi*16 + lo16)<<9) + kk*32 + quad*8];
      arz[mi]   = MFMA16(a, b0, arz[mi]);
      arz[4+mi] = MFMA16(a, b1, arz[4+mi]);
      an_[mi]   = MFMA16(a, b2, an_[mi]);
    }
  }
  #pragma unroll 2
  for (int kk = 0; kk < 16; ++kk) {
    const f16x8 b0 = *(const f16x8*)(WhhSw + (((long)Wt*16 + kk)<<9)      + lane*8);
    const f16x8 b1 = *(const f16x8*)(WhhSw + (((long)(32+Wt)*16 + kk)<<9) + lane*8);
    const f16x8 b2 = *(const f16x8*)(WhhSw + (((long)(64+Wt)*16 + kk)<<9) + lane*8);
    #pragma unroll
    for (int mi = 0; mi < 4; ++mi) {
      const f16x8 a = *(const f16x8*)&hin[((mi*16 + lo16)<<9) + kk*32 + quad*8];
      arz[mi]   = MFMA16(a, b0, arz[mi]);
      arz[4+mi] = MFMA16(a, b1, arz[4+mi]);
      an_[4+mi] = MFMA16(a, b2, an_[4+mi]);
    }
  }
  const int c = Wt*16 + lo16;
  const float brz0 = bih[c]     + bhh[c];
  const float brz1 = bih[512+c] + bhh[512+c];
  const float bin_ = bih[1024+c];
  const float bhn_ = bhh[1024+c];
  #pragma unroll
  for (int mi = 0; mi < 4; ++mi)
    #pragma unroll
    for (int r = 0; r < 4; ++r) {
      const int row = mi*16 + quad*4 + r;
      const float rv = sigm_(clampf(arz[mi][r],64.f)   + brz0);
      const float zv = sigm_(clampf(arz[4+mi][r],64.f) + brz1);
      const float nv = tanh_(clampf(an_[mi][r],64.f) + bin_ + rv*(clampf(an_[4+mi][r],64.f) + bhn_));
      const float ho = hf32[(row<<9) + c];
      float hn2 = (1.f - zv)*nv + zv*ho;
      hn2 = clampf(hn2, 2.f);
      hf32[(row<<9) + c] = hn2;
      hout[(row<<9) + c] = (f16)hn2;
      if (cat) cat[(row<<10) + c] = (f16)hn2;
    }
}

// ---------- final projection ----------
__global__ void k_out(const float* __restrict__ h2, const float* __restrict__ fcW,
                      const float* __restrict__ fcb, float* __restrict__ out, int step)
{
  const int b = blockIdx.x, t = threadIdx.x;
  __shared__ float r0[256], r1[256];
  const float ha = clampf(h2[(b<<9) + t], 2.f);
  const float hb = clampf(h2[(b<<9) + 256 + t], 2.f);
  r0[t] = ha*fcW[t]     + hb*fcW[256+t];
  r1[t] = ha*fcW[512+t] + hb*fcW[768+t];
  __syncthreads();
  for (int off = 128; off > 0; off >>= 1) {
    if (t < off) { r0[t] += r0[t+off]; r1[t] += r1[t+off]; }
    __syncthreads();
  }
  if (t == 0) {
    out[(b*24 + step)*2]     = clampf(r0[0] + fcb[0], 128.f);
    out[(b*24 + step)*2 + 1] = clampf(r1[0] + fcb[1], 128.f);
  }
}

extern "C" void kernel_launch(void* const* d_in, const int* in_sizes, int n_in,
                              void* d_out, int out_size, void* d_ws, size_t ws_size,
                              hipStream_t stream) {
  const float* X      = (const float*)d_in[0];
  const float* eWih0  = (const float*)d_in[1];
  const float* eWhh0  = (const float*)d_in[2];
  const float* ebih0  = (const float*)d_in[3];
  const float* ebhh0  = (const float*)d_in[4];
  const float* eWih   = (const float*)d_in[5];
  const float* eWhh   = (const float*)d_in[6];
  const float* ebih   = (const float*)d_in[7];
  const float* ebhh   = (const float*)d_in[8];
  const float* dWih   = (const float*)d_in[9];
  const float* dWhh   = (const float*)d_in[10];
  const float* dbih   = (const float*)d_in[11];
  const float* dbhh   = (const float*)d_in[12];
  const float* fcconW = (const float*)d_in[13];
  const float* fcconB = (const float*)d_in[14];
  const float* attnW  = (const float*)d_in[15];
  const float* attnB  = (const float*)d_in[16];
  const float* vW     = (const float*)d_in[17];
  const float* fcW    = (const float*)d_in[18];
  const float* fcB    = (const float*)d_in[19];
  float* OUT = (float*)d_out;

  const long need_big  = 47054848L;
  const long need_half = 32964608L;
  f16* H = (f16*)d_ws;
  f16 *SEQ = H, *L1OUT, *GIB, *R3, *FIN, *HB, *CAT, *INP;
  float *HC;
  int BH, lbh, nh, l1ostr, l1abstr; long gdir;

  if ((long)ws_size >= need_big) {
    BH = 64; lbh = 6; nh = 1; l1ostr = 64; l1abstr = 64;
    L1OUT = H + 8388608L;
    GIB   = H + 16777216L;
    HC    = (float*)(H + 23068672L);
    FIN   = H + 23134208L;
    HB    = H + 23232512L;
    CAT   = H + 23429120L;
    INP   = H + 23494656L;
    gdir  = 3145728L;
  } else if ((long)ws_size >= need_half) {
    BH = 32; lbh = 5; nh = 2; l1ostr = 32; l1abstr = 32;
    L1OUT = H + 8388608L;
    GIB   = H + 12582912L;
    HC    = (float*)(H + 16023552L);
    FIN   = H + 16089088L;
    HB    = H + 16187392L;
    CAT   = H + 16384000L;
    INP   = H + 16449536L;
    gdir  = 1572864L;
  } else {
    k_diag<<<12, 256, 0, stream>>>(OUT, (int)(ws_size >> 20));
    return;
  }
  R3 = GIB;
  float* ST = (float*)(GIB + 3145728L);
  float* HQ = ST;
  float* HF = ST + 32768;
  float* S  = ST + 131072;
  u32* CNT = (u32*)ST;              // big path only (HQ unused there)
  const int nblk = 2*(BH>>4);
  const int gi0grid = (2*64*BH*768)/256;

  for (int h = 0; h < nh; ++h) {
    const int b0 = h*BH;
    for (int seg = 0; seg < 4; ++seg) {
      k_gi0s<<<gi0grid, 256, 0, stream>>>(X, eWih0, ebih0, GIB, seg, BH, lbh, b0);
      k_enc_seg<<<nblk, 512, 0, stream>>>(GIB, eWhh0, ebhh0, SEQ + (long)b0*512, 64,
                                          FIN + (long)b0*512, HC, seg, BH);
    }
    for (int seg = 0; seg < 4; ++seg) {
      if (BH == 64)
        k_gemm_gi<<<dim3(64, 4, 2), 256, 0, stream>>>(SEQ, eWih, 393216L, ebih,
            GIB, seg*64, 255 - seg*64, 1, 64, 32.f);
      else
        k_gemm<<<dim3(BH, 6, 2), 256, 0, stream>>>(SEQ + (long)b0*512, 512,
            (const f16*)nullptr, eWih, 393216L, 512, 0, ebih, 768,
            GIB, gdir, 768, 2, seg*64, 255 - seg*64, 1, lbh, 64, 32.f);
      k_enc_seg<<<nblk, 512, 0, stream>>>(GIB, eWhh, ebhh, L1OUT, l1ostr,
                                          FIN + 32768 + (long)b0*512, HC, seg, BH);
    }
    for (int seg = 0; seg < 4; ++seg) {
      if (BH == 64)
        k_gemm_gi<<<dim3(64, 4, 2), 256, 0, stream>>>(L1OUT, eWih + 2L*393216,
            393216L, ebih + 1536, GIB, seg*64, 255 - seg*64, 1, 64, 32.f);
      else
        k_gemm<<<dim3(BH, 6, 2), 256, 0, stream>>>(L1OUT, 512,
            (const f16*)nullptr, eWih + 2L*393216, 393216L, 512, 0, ebih + 1536, 768,
            GIB, gdir, 768, 2, seg*64, 255 - seg*64, 1, lbh, l1abstr, 32.f);
      k_enc_seg<<<nblk, 512, 0, stream>>>(GIB, eWhh + 2L*196608, ebhh + 1536,
                                          SEQ + (long)b0*512, 64,
                                          FIN + 65536 + (long)b0*512, HC, seg, BH);
    }
  }

  if (BH == 64) {
    f16* EP    = L1OUT;              // [64][256][512] f16 enc_proj (+attn_b), mode-3 layout
    f16* WIHSW = GIB + 3440640L;
    f16* WHSW  = GIB + 5799936L;

    k_prep_dec<<<2816, 256, 0, stream>>>(dWhh, attnW, fcconW, dWih, R3);
    k_gemm<<<dim3(256, 4, 1), 256, 0, stream>>>(SEQ, 512,
        R3 + 2359296L, (const float*)nullptr, 0L, 0, 0, attnB, 0,
        EP, 0L, 512, 3, 0, 0, 1, 6, 64, 32.f);
    k_dec_init<<<512, 256, 0, stream>>>(FIN, SEQ, HB, HF, CAT, CNT);

    k_dec_loop<<<64, 512, 0, stream>>>(SEQ, EP, CAT, WHSW, R3 + 2621440L,
        fcconB, vW, INP, fcW, fcB, OUT,
        WIHSW, R3, dbih, dbhh, HF, HB, CNT);
    k_out<<<64, 256, 0, stream>>>(HF + 2*32768, fcW, fcB, OUT, 23);
  } else {
    k_prep_dec<<<1536, 256, 0, stream>>>(dWhh, attnW, fcconW, dWih, R3);
    k_dec_init<<<512, 256, 0, stream>>>(FIN, SEQ, HB, HF, CAT, (u32*)(S + 16000));

    for (int s = 0; s < 24; ++s) {
      const int p = s & 1;
      const f16* h2in = HB + (4 + p)*32768L;
      k_gemm<<<dim3(1,4,1), 256, 0, stream>>>(h2in, 512,
          (const f16*)nullptr, attnW, 0L, 1024, 0, (const float*)nullptr, 0,
          HQ, 0L, 512, 0, 0, 0, 0, 6, 64, 64.f);
      k_score<<<256, 256, 0, stream>>>(SEQ, R3 + 2359296L, HQ, attnB, vW, S);
      k_attnctx<<<64, 256, 0, stream>>>(S, SEQ, CAT);
      k_gemm<<<dim3(1,4,1), 256, 0, stream>>>(CAT, 1024,
          R3 + 2621440L, (const float*)nullptr, 0L, 0, 0, fcconB, 0,
          INP, 0L, 512, 1, 0, 0, 0, 6, 64, 64.f);
      for (int l = 0; l < 3; ++l) {
        const f16* inp = (l == 0) ? INP : (HB + (2*(l-1) + (1-p))*32768L);
        k_cell_raw<<<8, 256, 0, stream>>>(inp,
                  dWih + (long)l*786432, R3 + (long)l*786432,
                  dbih + l*1536, dbhh + l*1536, HF + (long)l*32768,
                  HB + (2*l + p)*32768L, HB + (2*l + (1-p))*32768L,
                  (l == 2) ? CAT : (f16*)nullptr);
      }
      k_out<<<64, 256, 0, stream>>>(HF + 2*32768, fcW, fcB, OUT, s);
    }
  }
}

// Round 11
// 6060.695 us; speedup vs baseline: 1.8752x; 1.8752x over previous
//
#include <hip/hip_runtime.h>

typedef unsigned short u16;
typedef unsigned int u32;
typedef _Float16 f16;
typedef f16   f16x2 __attribute__((ext_vector_type(2)));
typedef f16   f16x4 __attribute__((ext_vector_type(4)));
typedef f16   f16x8 __attribute__((ext_vector_type(8)));
typedef float f32x4 __attribute__((ext_vector_type(4)));

#define MFMA16(a,b,c) __builtin_amdgcn_mfma_f32_16x16x32_f16((a),(b),(c),0,0,0)

__device__ __forceinline__ float sigm_(float x){ return 1.f/(1.f + __expf(-x)); }
__device__ __forceinline__ float tanh_(float x){ return 1.f - 2.f/(1.f + __expf(2.f*x)); }
__device__ __forceinline__ float clampf(float x, float c){
  if (!(x > -c)) x = -c;
  if (x > c) x = c;
  return x;
}
__device__ __forceinline__ f16x8 cvt8f(const float* p){
  const float4 a = *(const float4*)p;
  const float4 b = *(const float4*)(p+4);
  f16x8 r;
  r[0]=(f16)a.x; r[1]=(f16)a.y; r[2]=(f16)a.z; r[3]=(f16)a.w;
  r[4]=(f16)b.x; r[5]=(f16)b.y; r[6]=(f16)b.z; r[7]=(f16)b.w;
  return r;
}

// narrow 8-member device barrier (per-mi-group); throttled spin, unique counter line
__device__ __forceinline__ void gbar8_(u32* c){
  __syncthreads();
  __threadfence();
  if (threadIdx.x == 0) {
    __hip_atomic_fetch_add(c, 1u, __ATOMIC_RELAXED, __HIP_MEMORY_SCOPE_AGENT);
    while (__hip_atomic_load(c, __ATOMIC_RELAXED, __HIP_MEMORY_SCOPE_AGENT) < 8u)
      __builtin_amdgcn_s_sleep(2);
  }
  __syncthreads();
  __threadfence();
}

// ---------- diagnostic ----------
__global__ void k_diag(float* out, int mib){
  const int i = blockIdx.x*256 + threadIdx.x;
  if (i < 3072) out[i] = 1000.f * (float)mib;
}

// ---------- decoder weight swizzle (fp32 -> f16 MFMA B-frags) ----------
__global__ void k_prep_dec(const float* dWhh, const float* attnW, const float* fccon,
                           const float* dWih, f16* R3)
{
  long idx = (long)blockIdx.x*256 + threadIdx.x;
  const float* src; int rs, colOff = 0, NKS; long dst, loc;
  if (idx < 294912L) {
    loc = idx; const int m = (int)(loc / 98304); loc %= 98304;
    src = dWhh + (long)m*786432; rs = 512; NKS = 16; dst = (long)m*786432;
  } else if (idx < 327680L) {
    loc = idx - 294912L; src = attnW; colOff = 512; rs = 1024; NKS = 16; dst = 2359296L;
  } else if (idx < 393216L) {
    loc = idx - 327680L; src = fccon; rs = 1024; NKS = 32; dst = 2621440L;
  } else if (idx < 688128L) {
    loc = idx - 393216L; const int m = (int)(loc / 98304); loc %= 98304;
    src = dWih + (long)m*786432; rs = 512; NKS = 16; dst = 3440640L + (long)m*786432;
  } else if (idx < 720896L) {
    loc = idx - 688128L; src = attnW; colOff = 0; rs = 1024; NKS = 16; dst = 5799936L;
  } else return;
  const int lane = (int)(loc & 63);
  const long frag = loc >> 6;
  const int ks = (int)(frag % NKS);
  const long nt = frag / NKS;
  const int n  = (int)(nt*16 + (lane & 15));
  const int k0 = ks*32 + ((lane >> 4) << 3);
  const float* sp = src + (long)n*rs + colOff + k0;
  f16* dp = R3 + dst + loc*8;
  #pragma unroll
  for (int j = 0; j < 8; ++j) dp[j] = (f16)sp[j];
}

// ---------- layer-0 gi, v2 layout: per-thread-contiguous 24 f16 ----------
__global__ void k_gi0s(const float* __restrict__ x, const float* __restrict__ W,
                       const float* __restrict__ bi, f16* __restrict__ gi,
                       int seg, int BH, int lbh, int b0)
{
  const long idx = (long)blockIdx.x*256 + threadIdx.x;
  const int v = (int)(idx % 24);
  long rest = idx / 24;
  const int tid = (int)(rest & 511); rest >>= 9;
  const int bq = (int)(rest & ((1 << (lbh-4)) - 1)); rest >>= (lbh-4);
  const int s = (int)(rest & 63);
  const int d = (int)(rest >> 6);
  const int r = v / 6, rem = v % 6, i = rem / 3, g = rem % 3;
  const int w = tid >> 6, q = (tid >> 4) & 3, lo = tid & 15;
  const int n = g*256 + (2*w + i)*16 + lo;
  const int b = bq*16 + q*4 + r;
  const int t = d ? (255 - (seg*64 + s)) : (seg*64 + s);
  const float x0 = x[(((b0+b)<<8) + t)*2];
  const float x1 = x[(((b0+b)<<8) + t)*2 + 1];
  const long wi = ((long)d*768 + n)*2;
  gi[idx] = (f16)clampf(x0*W[wi] + x1*W[wi+1] + bi[d*768 + n], 32.f);
}

// gi element accessor: 24 contiguous f16 held as 3 x f16x8
#define GIE(G, vv) ((float)((vv) < 8 ? (G)[0][(vv)&7] : ((vv) < 16 ? (G)[1][(vv)-8] : (G)[2][(vv)-16])))

// ---------- encoder recurrence: 512 thr / 8 waves (round-3/6/8/9 proven version) ----------
__global__ __launch_bounds__(512, 1) void k_enc_seg(
    const f16* __restrict__ gi, const float* __restrict__ Wraw,
    const float* __restrict__ bhh, f16* __restrict__ seq, int ostr,
    f16* __restrict__ fin, float* __restrict__ hcar, int seg, int BH)
{
  const int tid = threadIdx.x;
  const int w = tid >> 6, lane = tid & 63;
  const int lo16 = lane & 15, quad = lane >> 4;
  const int nbq = BH >> 4;
  const int dir = blockIdx.x / nbq, bq = blockIdx.x % nbq;

  __shared__ f16 h16[4][16][264];   // 4-deep ring: read s&3, write (s+1)&3, flush (s-1)&3

  const float* mat = Wraw + (long)dir*196608;   // [768][256] fp32
  f16x8 wr[6][8];
  #pragma unroll
  for (int p = 0; p < 3; ++p)
    #pragma unroll
    for (int i = 0; i < 2; ++i) {
      const int n = (p*16 + 2*w + i)*16 + lo16;
      #pragma unroll
      for (int ks = 0; ks < 8; ++ks)
        wr[p*2+i][ks] = cvt8f(mat + (long)n*256 + ks*32 + quad*8);
    }
  float bh_[3][2];
  #pragma unroll
  for (int p = 0; p < 3; ++p)
    #pragma unroll
    for (int i = 0; i < 2; ++i)
      bh_[p][i] = bhh[dir*768 + p*256 + (2*w+i)*16 + lo16];

  float hreg[2][4];
  if (seg == 0) {
    #pragma unroll
    for (int i = 0; i < 2; ++i)
      #pragma unroll
      for (int r = 0; r < 4; ++r) {
        hreg[i][r] = 0.f;
        h16[0][quad*4 + r][(2*w+i)*16 + lo16] = (f16)0.f;
      }
  } else {
    #pragma unroll
    for (int i = 0; i < 2; ++i) {
      const int c = (2*w+i)*16 + lo16;
      #pragma unroll
      for (int r = 0; r < 4; ++r) {
        const float v = hcar[((dir*BH) + bq*16 + quad*4 + r)*256 + c];
        hreg[i][r] = v;
        h16[0][quad*4 + r][c] = (f16)v;
      }
    }
  }

  const long gstep = (long)nbq*512*24;
  const f16* gbase = gi + (((long)dir*64*nbq + bq)*512 + tid)*24;
  f16x8 g0[3], g1[3];
  { const f16x8* gp = (const f16x8*)gbase; g0[0]=gp[0]; g0[1]=gp[1]; g0[2]=gp[2]; }

  const int frow = tid >> 5;        // flush mapping: 512 thr -> 16 rows x 32 col8
  const int fcol = (tid & 31) * 8;

  for (int s = 0; s < 64; ++s) {
    __syncthreads();                // h16[(s&3)] (written prev iter) visible
    if (s >= 2) {
      const int so = s - 2;
      const int t2 = dir ? (255 - (seg*64 + so)) : (seg*64 + so);
      const f16x8 hv = *(const f16x8*)&h16[(so+1)&3][frow][fcol];
      *(f16x8*)&seq[((long)t2*ostr + bq*16 + frow)*512 + dir*256 + fcol] = hv;
    }
    f32x4 acc[6];
    #pragma unroll
    for (int q = 0; q < 6; ++q) acc[q] = (f32x4){0.f,0.f,0.f,0.f};
    #pragma unroll
    for (int ks = 0; ks < 8; ++ks) {
      const f16x8 a = *(const f16x8*)&h16[s&3][lo16][ks*32 + quad*8];
      #pragma unroll
      for (int q = 0; q < 6; ++q)
        acc[q] = MFMA16(a, wr[q][ks], acc[q]);
    }
    if (s < 63) {
      const f16x8* gp = (const f16x8*)(gbase + (long)(s+1)*gstep);
      g1[0]=gp[0]; g1[1]=gp[1]; g1[2]=gp[2];
    }
    #pragma unroll
    for (int i = 0; i < 2; ++i) {
      const int c = (2*w+i)*16 + lo16;
      #pragma unroll
      for (int r = 0; r < 4; ++r) {
        const int row = quad*4 + r;
        const int v = r*6 + i*3;
        const float gir = GIE(g0, v);
        const float giz = GIE(g0, v+1);
        const float gin = GIE(g0, v+2);
        const float rv = sigm_(gir + acc[i][r]   + bh_[0][i]);
        const float zv = sigm_(giz + acc[2+i][r] + bh_[1][i]);
        const float nv = tanh_(gin + rv*(acc[4+i][r] + bh_[2][i]));
        float hn = (1.f - zv)*nv + zv*hreg[i][r];
        hn = clampf(hn, 2.f);
        hreg[i][r] = hn;
        h16[(s+1)&3][row][c] = (f16)hn;
        if (seg == 3 && s == 63) fin[(bq*16 + row)*512 + dir*256 + c] = (f16)hn;
      }
    }
    g0[0]=g1[0]; g0[1]=g1[1]; g0[2]=g1[2];
  }
  __syncthreads();
  #pragma unroll
  for (int so = 62; so < 64; ++so) {
    const int t2 = dir ? (255 - (seg*64 + so)) : (seg*64 + so);
    const f16x8 hv = *(const f16x8*)&h16[(so+1)&3][frow][fcol];
    *(f16x8*)&seq[((long)t2*ostr + bq*16 + frow)*512 + dir*256 + fcol] = hv;
  }
  #pragma unroll
  for (int i = 0; i < 2; ++i) {
    const int c = (2*w+i)*16 + lo16;
    #pragma unroll
    for (int r = 0; r < 4; ++r)
      hcar[((dir*BH) + bq*16 + quad*4 + r)*256 + c] = hreg[i][r];
  }
}

// ---------- big-path gi GEMM, j-quarter split: grid (64,4,2), acc[12] (round-8 proven) ----------
__global__ void k_gemm_gi(const f16* __restrict__ A,
                          const float* __restrict__ Braw, long bzs,
                          const float* __restrict__ bias,
                          f16* __restrict__ gi,
                          int tb0, int tb1, int tdirsgn, int abstr, float cv)
{
  const int tid = threadIdx.x, w = tid>>6, lane = tid&63;
  const int lo16 = lane&15, quad = lane>>4;
  const int s_ = blockIdx.x;
  const int y  = blockIdx.y;          // j-quarter 0..3
  const int z  = blockIdx.z;
  const int tbase = z ? tb1 : tb0;
  const int tdir  = z ? -tdirsgn : tdirsgn;
  const int mrow = s_*64 + w*16 + lo16;
  const long arow = (long)(tbase + tdir*(mrow >> 6))*abstr + (mrow & 63);
  const f16* Ap = A + arow*512 + quad*8;
  const float* Bp = Braw + (long)z*bzs;
  f32x4 acc[12];
  #pragma unroll
  for (int i=0;i<12;++i) acc[i]=(f32x4){0.f,0.f,0.f,0.f};
  for (int ks = 0; ks < 16; ++ks) {
    const f16x8 a = *(const f16x8*)(Ap + ks*32);
    #pragma unroll
    for (int g = 0; g < 3; ++g)
      #pragma unroll
      for (int jj = 0; jj < 4; ++jj) {
        const int n = g*256 + y*64 + jj*16 + lo16;
        const f16x8 b = cvt8f(Bp + (long)n*512 + ks*32 + quad*8);
        acc[g*4+jj] = MFMA16(a, b, acc[g*4+jj]);
      }
  }
  f16* base = gi + (((long)z*64 + s_)*4 + w)*12288L;
  #pragma unroll
  for (int l = 0; l < 2; ++l) {       // consumer w_c = y*2 + l ; jj = l*2 + jl
    f16x8 rec8[3];
    #pragma unroll
    for (int r = 0; r < 4; ++r)
      #pragma unroll
      for (int jl = 0; jl < 2; ++jl)
        #pragma unroll
        for (int g = 0; g < 3; ++g) {
          const int nt = g*4 + l*2 + jl;
          const int n = g*256 + y*64 + (l*2+jl)*16 + lo16;
          const int slot = r*6 + jl*3 + g;
          rec8[slot>>3][slot&7] = (f16)clampf(acc[nt][r] + bias[z*768 + n], cv);
        }
    f16* dp = base + ((long)(y*2 + l)*64 + quad*16 + lo16)*24L;
    *(f16x8*)(dp)      = rec8[0];
    *(f16x8*)(dp + 8)  = rec8[1];
    *(f16x8*)(dp + 16) = rec8[2];
  }
}

// ---------- MFMA GEMM; mode 0=f32 C, 1=f16 C, 2=f16 C gi-v2, 3=f16 C [b][t] transposed ----------
__global__ void k_gemm(const f16* __restrict__ A, int K,
                       const f16* __restrict__ Bsw, const float* __restrict__ Braw,
                       long bzs, int ldb, int koff,
                       const float* __restrict__ bias, int biaszs,
                       void* __restrict__ Cv, long czs, int ldc, int mode,
                       int tb0, int tb1, int tdirsgn, int lbh, int abstr, float cv)
{
  const int tid = threadIdx.x, w = tid>>6, lane = tid&63;
  const int lo16 = lane&15, quad = lane>>4;
  const int m0 = blockIdx.x*64 + w*16;
  const int n0 = blockIdx.y*128;
  const int z  = blockIdx.z;
  const int tbase = z ? tb1 : tb0;
  const int tdir  = z ? -tdirsgn : tdirsgn;
  const int NKS = K >> 5;
  const int mrow = m0 + lo16;
  const long arow = (long)(tbase + tdir*(mrow >> lbh))*abstr + (mrow & ((1<<lbh)-1));
  const f16* Ap = A + arow*K + quad*8;
  f32x4 acc[8];
  #pragma unroll
  for (int i=0;i<8;++i) acc[i]=(f32x4){0.f,0.f,0.f,0.f};
  if (Bsw) {
    const f16* Bp = Bsw + (long)z*bzs;
    for (int ks = 0; ks < NKS; ++ks) {
      const f16x8 a = *(const f16x8*)(Ap + ks*32);
      #pragma unroll
      for (int nt = 0; nt < 8; ++nt) {
        const f16x8 b = *(const f16x8*)(Bp + (((long)((n0>>4)+nt)*NKS + ks) << 9) + lane*8);
        acc[nt] = MFMA16(a, b, acc[nt]);
      }
    }
  } else {
    const float* Bp = Braw + (long)z*bzs;
    for (int ks = 0; ks < NKS; ++ks) {
      const f16x8 a = *(const f16x8*)(Ap + ks*32);
      #pragma unroll
      for (int nt = 0; nt < 8; ++nt) {
        const f16x8 b = cvt8f(Bp + (long)(n0 + nt*16 + lo16)*ldb + koff + ks*32 + quad*8);
        acc[nt] = MFMA16(a, b, acc[nt]);
      }
    }
  }
  #pragma unroll
  for (int nt = 0; nt < 8; ++nt) {
    const int n = n0 + nt*16 + lo16;
    const float bv = bias ? bias[z*biaszs + n] : 0.f;
    #pragma unroll
    for (int r = 0; r < 4; ++r) {
      const int m = m0 + quad*4 + r;
      const float val = clampf(acc[nt][r] + bv, cv);
      if (mode == 2) {
        const int s_ = m >> lbh, b_ = m & ((1<<lbh)-1);
        const int bq_ = b_ >> 4, q_ = (b_ >> 2) & 3, r_ = b_ & 3;
        const int g_ = n >> 8, j_ = (n >> 4) & 15, lo_ = n & 15;
        const long idx = ((((long)z*64 + s_)*(1<<(lbh-4)) + bq_)*512
                          + ((j_>>1)*64 + q_*16 + lo_))*24 + r_*6 + (j_&1)*3 + g_;
        ((f16*)Cv)[idx] = (f16)val;
      } else if (mode == 3)
        ((f16*)Cv)[(((long)(m & 63) << 8) + (m >> 6))*512 + n] = (f16)val;
      else if (mode == 1)
        ((f16*)Cv)[(long)z*czs + (long)m*ldc + n] = (f16)val;
      else
        ((float*)Cv)[(long)z*czs + (long)m*ldc + n] = val;
    }
  }
}

// ---------- (half path only) fused proj+score ----------
__global__ void k_score(const f16* __restrict__ seq, const f16* __restrict__ We,
                        const float* __restrict__ hq, const float* __restrict__ ab,
                        const float* __restrict__ vp, float* __restrict__ S)
{
  const int t = blockIdx.x, tid = threadIdx.x;
  const int w = tid>>6, lane = tid&63, lo16 = lane&15, quad = lane>>4;
  __shared__ float svab[1024];
  for (int i = tid; i < 512; i += 256) { svab[i] = vp[i]; svab[512+i] = ab[i]; }
  __syncthreads();
  f32x4 acc[32];
  #pragma unroll
  for (int i=0;i<32;++i) acc[i]=(f32x4){0.f,0.f,0.f,0.f};
  const f16* Ap = seq + ((long)t*64 + w*16 + lo16)*512 + quad*8;
  for (int ks = 0; ks < 16; ++ks) {
    const f16x8 a = *(const f16x8*)(Ap + ks*32);
    #pragma unroll
    for (int nt = 0; nt < 32; ++nt) {
      const f16x8 b = *(const f16x8*)(We + (((long)nt*16 + ks) << 9) + lane*8);
      acc[nt] = MFMA16(a, b, acc[nt]);
    }
  }
  #pragma unroll
  for (int r = 0; r < 4; ++r) {
    const int b = w*16 + quad*4 + r;
    float sc = 0.f;
    #pragma unroll
    for (int nt = 0; nt < 32; ++nt) {
      const int n = nt*16 + lo16;
      sc += svab[n] * tanh_(acc[nt][r] + hq[(b<<9) + n] + svab[512+n]);
    }
    sc += __shfl_xor(sc, 1, 64); sc += __shfl_xor(sc, 2, 64);
    sc += __shfl_xor(sc, 4, 64); sc += __shfl_xor(sc, 8, 64);
    if (lo16 == 0) S[(b<<8) + t] = clampf(sc, 256.f);
  }
}

// ---------- (half path only) softmax + context ----------
__global__ void k_attnctx(const float* __restrict__ S, const f16* __restrict__ enc,
                          f16* __restrict__ cat)
{
  const int b = blockIdx.x, tid = threadIdx.x;
  __shared__ float ssc[256], srd[256];
  const float sc = clampf(S[(b<<8) + tid], 256.f);
  srd[tid] = sc; __syncthreads();
  for (int off = 128; off > 0; off >>= 1) { if (tid < off) srd[tid] = fmaxf(srd[tid], srd[tid+off]); __syncthreads(); }
  const float mx = srd[0]; __syncthreads();
  const float e = __expf(sc - mx);
  srd[tid] = e; __syncthreads();
  for (int off = 128; off > 0; off >>= 1) { if (tid < off) srd[tid] += srd[tid+off]; __syncthreads(); }
  const float inv = 1.f / srd[0]; __syncthreads();
  ssc[tid] = e * inv; __syncthreads();
  float c0 = 0.f, c1 = 0.f;
  for (int tt = 0; tt < 256; ++tt) {
    const float awt = ssc[tt];
    const f16* ep = enc + (((long)tt*64 + b) << 9);
    c0 += awt * (float)ep[tid];
    c1 += awt * (float)ep[256 + tid];
  }
  cat[(b<<10) + 512 + tid] = (f16)clampf(c0, 4.f);
  cat[(b<<10) + 768 + tid] = (f16)clampf(c1, 4.f);
}

// ---------- decoder init (also zeroes barrier counters) ----------
__global__ void k_dec_init(const f16* __restrict__ fin, const f16* __restrict__ seq,
                           f16* __restrict__ hb16, float* __restrict__ hf32,
                           f16* __restrict__ cat, u32* __restrict__ cnt)
{
  const int idx = blockIdx.x*256 + threadIdx.x;
  if (idx < 3072) cnt[idx] = 0;
  const int d = idx & 511, b = (idx >> 9) & 63, l = idx >> 15;
  if (l < 3) {
    const float v = clampf((float)fin[((long)l<<15) + (b<<9) + d], 2.f);
    hb16[(long)l*65536 + (b<<9) + d] = (f16)v;
    hf32[(long)l*32768 + (b<<9) + d] = v;
  } else {
    cat[(b<<10) + d] = seq[((long)255*64 + b)*512 + d];
  }
}

// ---------- fused attention step (big path); ep in [b][t][512] layout ----------
__global__ __launch_bounds__(512, 1) void k_attn(
    const f16* __restrict__ seq, const f16* __restrict__ ep,
    const float* __restrict__ hf2, const f16* __restrict__ cat,
    const f16* __restrict__ whsw, const f16* __restrict__ fcsw,
    const float* __restrict__ fcconB, const float* __restrict__ vp,
    f16* __restrict__ inp, const float* __restrict__ fcW,
    const float* __restrict__ fcb, float* __restrict__ out, int step)
{
  const int b = blockIdx.x;
  const int tid = threadIdx.x, w = tid >> 6, lane = tid & 63;
  const int quad = lane >> 4;
  __shared__ float hsm[512];
  __shared__ float cats[1024];
  __shared__ float hqs[512];
  __shared__ float aw[256];
  __shared__ float red[8*512];
  hsm[tid]  = hf2[(b<<9) + tid];
  cats[tid] = (float)cat[(b<<10) + tid];
  __syncthreads();
  if (w < 2 && step > 0) {
    float p = 0.f;
    #pragma unroll
    for (int j = 0; j < 8; ++j) p += fcW[(w<<9) + lane*8 + j] * hsm[lane*8 + j];
    p += __shfl_xor(p,1,64); p += __shfl_xor(p,2,64); p += __shfl_xor(p,4,64);
    p += __shfl_xor(p,8,64); p += __shfl_xor(p,16,64); p += __shfl_xor(p,32,64);
    if (lane == 0) out[(b*24 + step-1)*2 + w] = clampf(p + fcb[w], 128.f);
  }
  #pragma unroll
  for (int i = 0; i < 4; ++i) {
    const int nt = w*4 + i;
    float p = 0.f;
    for (int ks = 0; ks < 16; ++ks) {
      const f16x8 wv = *(const f16x8*)(whsw + (((long)nt*16 + ks)<<9) + lane*8);
      const float4 ha = *(const float4*)&hsm[ks*32 + quad*8];
      const float4 hb = *(const float4*)&hsm[ks*32 + quad*8 + 4];
      p += (float)wv[0]*ha.x + (float)wv[1]*ha.y + (float)wv[2]*ha.z + (float)wv[3]*ha.w
         + (float)wv[4]*hb.x + (float)wv[5]*hb.y + (float)wv[6]*hb.z + (float)wv[7]*hb.w;
    }
    p += __shfl_xor(p,16,64); p += __shfl_xor(p,32,64);
    if (lane < 16) hqs[nt*16 + lane] = p;
  }
  __syncthreads();
  float hq8[8], v8[8];
  #pragma unroll
  for (int j = 0; j < 8; ++j) { hq8[j] = hqs[lane*8+j]; v8[j] = vp[lane*8+j]; }
  #pragma unroll 2
  for (int i = 0; i < 32; ++i) {
    const int t = w*32 + i;
    const f16x8 e = *(const f16x8*)(ep + (((long)(b<<8) + t)<<9) + lane*8);
    float s = 0.f;
    #pragma unroll
    for (int j = 0; j < 8; ++j) s += v8[j]*tanh_((float)e[j] + hq8[j]);
    s += __shfl_xor(s,1,64); s += __shfl_xor(s,2,64); s += __shfl_xor(s,4,64);
    s += __shfl_xor(s,8,64); s += __shfl_xor(s,16,64); s += __shfl_xor(s,32,64);
    if (lane == 0) aw[t] = clampf(s, 256.f);
  }
  __syncthreads();
  if (tid < 64) {
    float s0=aw[tid], s1=aw[tid+64], s2=aw[tid+128], s3=aw[tid+192];
    float mx = fmaxf(fmaxf(s0,s1), fmaxf(s2,s3));
    mx = fmaxf(mx, __shfl_xor(mx,1,64)); mx = fmaxf(mx, __shfl_xor(mx,2,64));
    mx = fmaxf(mx, __shfl_xor(mx,4,64)); mx = fmaxf(mx, __shfl_xor(mx,8,64));
    mx = fmaxf(mx, __shfl_xor(mx,16,64)); mx = fmaxf(mx, __shfl_xor(mx,32,64));
    const float e0=__expf(s0-mx), e1=__expf(s1-mx), e2=__expf(s2-mx), e3=__expf(s3-mx);
    float sm = e0+e1+e2+e3;
    sm += __shfl_xor(sm,1,64); sm += __shfl_xor(sm,2,64); sm += __shfl_xor(sm,4,64);
    sm += __shfl_xor(sm,8,64); sm += __shfl_xor(sm,16,64); sm += __shfl_xor(sm,32,64);
    const float inv = 1.f/sm;
    aw[tid]=e0*inv; aw[tid+64]=e1*inv; aw[tid+128]=e2*inv; aw[tid+192]=e3*inv;
  }
  __syncthreads();
  float c8[8];
  #pragma unroll
  for (int j = 0; j < 8; ++j) c8[j] = 0.f;
  #pragma unroll 2
  for (int i = 0; i < 32; ++i) {
    const int t = w*32 + i;
    const f16x8 e = *(const f16x8*)(seq + (((long)t*64 + b)<<9) + lane*8);
    const float awt = aw[t];
    #pragma unroll
    for (int j = 0; j < 8; ++j) c8[j] += awt*(float)e[j];
  }
  #pragma unroll
  for (int j = 0; j < 8; ++j) red[(w<<9) + lane*8 + j] = c8[j];
  __syncthreads();
  {
    float s = 0.f;
    #pragma unroll
    for (int ww = 0; ww < 8; ++ww) s += red[(ww<<9) + tid];
    cats[512 + tid] = clampf(s, 4.f);
  }
  __syncthreads();
  #pragma unroll
  for (int i = 0; i < 4; ++i) {
    const int nt = w*4 + i;
    float p = 0.f;
    for (int ks = 0; ks < 32; ++ks) {
      const f16x8 wv = *(const f16x8*)(fcsw + (((long)nt*32 + ks)<<9) + lane*8);
      const float4 ca = *(const float4*)&cats[ks*32 + quad*8];
      const float4 cb = *(const float4*)&cats[ks*32 + quad*8 + 4];
      p += (float)wv[0]*ca.x + (float)wv[1]*ca.y + (float)wv[2]*ca.z + (float)wv[3]*ca.w
         + (float)wv[4]*cb.x + (float)wv[5]*cb.y + (float)wv[6]*cb.z + (float)wv[7]*cb.w;
    }
    p += __shfl_xor(p,16,64); p += __shfl_xor(p,32,64);
    if (lane < 16) inp[(b<<9) + nt*16 + lane] = (f16)clampf(p + fcconB[nt*16+lane], 64.f);
  }
}

// ---------- fused 3-layer decoder GRU (big path): 32 blocks, per-mi-group 8-member barriers ----------
// cnt layout per step: (l*4 + mi)*16  (2 transitions x 4 mi groups, 64B-spaced counters)
__global__ void k_cell3(const f16* __restrict__ inp0, const f16* __restrict__ WihSw,
                        const f16* __restrict__ WhhSw, const float* __restrict__ bihA,
                        const float* __restrict__ bhhA, float* __restrict__ hfA,
                        f16* __restrict__ hb, f16* __restrict__ cat, int p, u32* cnt)
{
  const int tid = threadIdx.x, w = tid>>6, lane = tid&63;
  const int lo16 = lane&15, quad = lane>>4;
  const int Wt = ((int)blockIdx.x & 7)*4 + w;     // 0..31
  const int mi = (int)blockIdx.x >> 3;            // 0..3 (16 rows each)
  for (int l = 0; l < 3; ++l) {
    const f16* inp = (l == 0) ? inp0 : (hb + (long)(2*(l-1) + (1-p))*32768);
    const f16* WihL = WihSw + (long)l*786432;
    const f16* WhhL = WhhSw + (long)l*786432;
    const float* bih = bihA + l*1536;
    const float* bhh = bhhA + l*1536;
    float* hf32 = hfA + (long)l*32768;
    const f16* hin = hb + (long)(2*l + p)*32768;
    f16* hout = hb + (long)(2*l + (1-p))*32768;
    f16* catp = (l == 2) ? cat : (f16*)nullptr;

    f32x4 arz[2], an_[2];
    #pragma unroll
    for (int i=0;i<2;++i){ arz[i]=(f32x4){0.f,0.f,0.f,0.f}; an_[i]=(f32x4){0.f,0.f,0.f,0.f}; }
    #pragma unroll 4
    for (int kk = 0; kk < 16; ++kk) {               // gi part (swizzled f16 Wih)
      const f16x8 b0 = *(const f16x8*)(WihL + (((long)Wt*16 + kk)<<9)      + lane*8);
      const f16x8 b1 = *(const f16x8*)(WihL + (((long)(32+Wt)*16 + kk)<<9) + lane*8);
      const f16x8 b2 = *(const f16x8*)(WihL + (((long)(64+Wt)*16 + kk)<<9) + lane*8);
      const f16x8 a = *(const f16x8*)&inp[((mi*16 + lo16)<<9) + kk*32 + quad*8];
      arz[0] = MFMA16(a, b0, arz[0]);
      arz[1] = MFMA16(a, b1, arz[1]);
      an_[0] = MFMA16(a, b2, an_[0]);
    }
    #pragma unroll 4
    for (int kk = 0; kk < 16; ++kk) {               // gh part
      const f16x8 b0 = *(const f16x8*)(WhhL + (((long)Wt*16 + kk)<<9)      + lane*8);
      const f16x8 b1 = *(const f16x8*)(WhhL + (((long)(32+Wt)*16 + kk)<<9) + lane*8);
      const f16x8 b2 = *(const f16x8*)(WhhL + (((long)(64+Wt)*16 + kk)<<9) + lane*8);
      const f16x8 a = *(const f16x8*)&hin[((mi*16 + lo16)<<9) + kk*32 + quad*8];
      arz[0] = MFMA16(a, b0, arz[0]);
      arz[1] = MFMA16(a, b1, arz[1]);
      an_[1] = MFMA16(a, b2, an_[1]);
    }
    const int c = Wt*16 + lo16;
    const float brz0 = bih[c]     + bhh[c];
    const float brz1 = bih[512+c] + bhh[512+c];
    const float bin_ = bih[1024+c];
    const float bhn_ = bhh[1024+c];
    #pragma unroll
    for (int r = 0; r < 4; ++r) {
      const int row = mi*16 + quad*4 + r;
      const float rv = sigm_(clampf(arz[0][r],64.f) + brz0);
      const float zv = sigm_(clampf(arz[1][r],64.f) + brz1);
      const float nv = tanh_(clampf(an_[0][r],64.f) + bin_ + rv*(clampf(an_[1][r],64.f) + bhn_));
      const float ho = hf32[(row<<9) + c];
      float hn2 = (1.f - zv)*nv + zv*ho;
      hn2 = clampf(hn2, 2.f);
      hf32[(row<<9) + c] = hn2;
      hout[(row<<9) + c] = (f16)hn2;
      if (catp) catp[(row<<10) + c] = (f16)hn2;
    }
    if (l < 2) gbar8_(cnt + (l*4 + mi)*16);
  }
}

// ---------- (half path only) original raw-Wih cell ----------
__global__ void k_cell_raw(const f16* __restrict__ inp, const float* __restrict__ WihRaw,
                           const f16* __restrict__ WhhSw, const float* __restrict__ bih,
                           const float* __restrict__ bhh, float* __restrict__ hf32,
                           const f16* __restrict__ hin, f16* __restrict__ hout,
                           f16* __restrict__ cat)
{
  const int tid = threadIdx.x, w = tid>>6, lane = tid&63;
  const int lo16 = lane&15, quad = lane>>4;
  const int Wt = blockIdx.x*4 + w;
  f32x4 arz[8], an_[8];
  #pragma unroll
  for (int i=0;i<8;++i){ arz[i]=(f32x4){0.f,0.f,0.f,0.f}; an_[i]=(f32x4){0.f,0.f,0.f,0.f}; }
  const int nr = Wt*16 + lo16;
  const float* Rr = WihRaw + (long)nr*512        + quad*8;
  const float* Rz = WihRaw + (long)(512+nr)*512  + quad*8;
  const float* Rn = WihRaw + (long)(1024+nr)*512 + quad*8;
  #pragma unroll 2
  for (int kk = 0; kk < 16; ++kk) {
    const f16x8 b0 = cvt8f(Rr + kk*32);
    const f16x8 b1 = cvt8f(Rz + kk*32);
    const f16x8 b2 = cvt8f(Rn + kk*32);
    #pragma unroll
    for (int mi = 0; mi < 4; ++mi) {
      const f16x8 a = *(const f16x8*)&inp[((mi*16 + lo16)<<9) + kk*32 + quad*8];
      arz[mi]   = MFMA16(a, b0, arz[mi]);
      arz[4+mi] = MFMA16(a, b1, arz[4+mi]);
      an_[mi]   = MFMA16(a, b2, an_[mi]);
    }
  }
  #pragma unroll 2
  for (int kk = 0; kk < 16; ++kk) {
    const f16x8 b0 = *(const f16x8*)(WhhSw + (((long)Wt*16 + kk)<<9)      + lane*8);
    const f16x8 b1 = *(const f16x8*)(WhhSw + (((long)(32+Wt)*16 + kk)<<9) + lane*8);
    const f16x8 b2 = *(const f16x8*)(WhhSw + (((long)(64+Wt)*16 + kk)<<9) + lane*8);
    #pragma unroll
    for (int mi = 0; mi < 4; ++mi) {
      const f16x8 a = *(const f16x8*)&hin[((mi*16 + lo16)<<9) + kk*32 + quad*8];
      arz[mi]   = MFMA16(a, b0, arz[mi]);
      arz[4+mi] = MFMA16(a, b1, arz[4+mi]);
      an_[4+mi] = MFMA16(a, b2, an_[4+mi]);
    }
  }
  const int c = Wt*16 + lo16;
  const float brz0 = bih[c]     + bhh[c];
  const float brz1 = bih[512+c] + bhh[512+c];
  const float bin_ = bih[1024+c];
  const float bhn_ = bhh[1024+c];
  #pragma unroll
  for (int mi = 0; mi < 4; ++mi)
    #pragma unroll
    for (int r = 0; r < 4; ++r) {
      const int row = mi*16 + quad*4 + r;
      const float rv = sigm_(clampf(arz[mi][r],64.f)   + brz0);
      const float zv = sigm_(clampf(arz[4+mi][r],64.f) + brz1);
      const float nv = tanh_(clampf(an_[mi][r],64.f) + bin_ + rv*(clampf(an_[4+mi][r],64.f) + bhn_));
      const float ho = hf32[(row<<9) + c];
      float hn2 = (1.f - zv)*nv + zv*ho;
      hn2 = clampf(hn2, 2.f);
      hf32[(row<<9) + c] = hn2;
      hout[(row<<9) + c] = (f16)hn2;
      if (cat) cat[(row<<10) + c] = (f16)hn2;
    }
}

// ---------- final projection ----------
__global__ void k_out(const float* __restrict__ h2, const float* __restrict__ fcW,
                      const float* __restrict__ fcb, float* __restrict__ out, int step)
{
  const int b = blockIdx.x, t = threadIdx.x;
  __shared__ float r0[256], r1[256];
  const float ha = clampf(h2[(b<<9) + t], 2.f);
  const float hb = clampf(h2[(b<<9) + 256 + t], 2.f);
  r0[t] = ha*fcW[t]     + hb*fcW[256+t];
  r1[t] = ha*fcW[512+t] + hb*fcW[768+t];
  __syncthreads();
  for (int off = 128; off > 0; off >>= 1) {
    if (t < off) { r0[t] += r0[t+off]; r1[t] += r1[t+off]; }
    __syncthreads();
  }
  if (t == 0) {
    out[(b*24 + step)*2]     = clampf(r0[0] + fcb[0], 128.f);
    out[(b*24 + step)*2 + 1] = clampf(r1[0] + fcb[1], 128.f);
  }
}

extern "C" void kernel_launch(void* const* d_in, const int* in_sizes, int n_in,
                              void* d_out, int out_size, void* d_ws, size_t ws_size,
                              hipStream_t stream) {
  const float* X      = (const float*)d_in[0];
  const float* eWih0  = (const float*)d_in[1];
  const float* eWhh0  = (const float*)d_in[2];
  const float* ebih0  = (const float*)d_in[3];
  const float* ebhh0  = (const float*)d_in[4];
  const float* eWih   = (const float*)d_in[5];
  const float* eWhh   = (const float*)d_in[6];
  const float* ebih   = (const float*)d_in[7];
  const float* ebhh   = (const float*)d_in[8];
  const float* dWih   = (const float*)d_in[9];
  const float* dWhh   = (const float*)d_in[10];
  const float* dbih   = (const float*)d_in[11];
  const float* dbhh   = (const float*)d_in[12];
  const float* fcconW = (const float*)d_in[13];
  const float* fcconB = (const float*)d_in[14];
  const float* attnW  = (const float*)d_in[15];
  const float* attnB  = (const float*)d_in[16];
  const float* vW     = (const float*)d_in[17];
  const float* fcW    = (const float*)d_in[18];
  const float* fcB    = (const float*)d_in[19];
  float* OUT = (float*)d_out;

  const long need_big  = 47054848L;
  const long need_half = 32964608L;
  f16* H = (f16*)d_ws;
  f16 *SEQ = H, *L1OUT, *GIB, *R3, *FIN, *HB, *CAT, *INP;
  float *HC;
  int BH, lbh, nh, l1ostr, l1abstr; long gdir;

  if ((long)ws_size >= need_big) {
    BH = 64; lbh = 6; nh = 1; l1ostr = 64; l1abstr = 64;
    L1OUT = H + 8388608L;
    GIB   = H + 16777216L;
    HC    = (float*)(H + 23068672L);
    FIN   = H + 23134208L;
    HB    = H + 23232512L;
    CAT   = H + 23429120L;
    INP   = H + 23494656L;
    gdir  = 3145728L;
  } else if ((long)ws_size >= need_half) {
    BH = 32; lbh = 5; nh = 2; l1ostr = 32; l1abstr = 32;
    L1OUT = H + 8388608L;
    GIB   = H + 12582912L;
    HC    = (float*)(H + 16023552L);
    FIN   = H + 16089088L;
    HB    = H + 16187392L;
    CAT   = H + 16384000L;
    INP   = H + 16449536L;
    gdir  = 1572864L;
  } else {
    k_diag<<<12, 256, 0, stream>>>(OUT, (int)(ws_size >> 20));
    return;
  }
  R3 = GIB;
  float* ST = (float*)(GIB + 3145728L);
  float* HQ = ST;
  float* HF = ST + 32768;
  float* S  = ST + 131072;
  u32* CNT = (u32*)ST;              // big path only (HQ unused there)
  const int nblk = 2*(BH>>4);
  const int gi0grid = (2*64*BH*768)/256;

  for (int h = 0; h < nh; ++h) {
    const int b0 = h*BH;
    for (int seg = 0; seg < 4; ++seg) {
      k_gi0s<<<gi0grid, 256, 0, stream>>>(X, eWih0, ebih0, GIB, seg, BH, lbh, b0);
      k_enc_seg<<<nblk, 512, 0, stream>>>(GIB, eWhh0, ebhh0, SEQ + (long)b0*512, 64,
                                          FIN + (long)b0*512, HC, seg, BH);
    }
    for (int seg = 0; seg < 4; ++seg) {
      if (BH == 64)
        k_gemm_gi<<<dim3(64, 4, 2), 256, 0, stream>>>(SEQ, eWih, 393216L, ebih,
            GIB, seg*64, 255 - seg*64, 1, 64, 32.f);
      else
        k_gemm<<<dim3(BH, 6, 2), 256, 0, stream>>>(SEQ + (long)b0*512, 512,
            (const f16*)nullptr, eWih, 393216L, 512, 0, ebih, 768,
            GIB, gdir, 768, 2, seg*64, 255 - seg*64, 1, lbh, 64, 32.f);
      k_enc_seg<<<nblk, 512, 0, stream>>>(GIB, eWhh, ebhh, L1OUT, l1ostr,
                                          FIN + 32768 + (long)b0*512, HC, seg, BH);
    }
    for (int seg = 0; seg < 4; ++seg) {
      if (BH == 64)
        k_gemm_gi<<<dim3(64, 4, 2), 256, 0, stream>>>(L1OUT, eWih + 2L*393216,
            393216L, ebih + 1536, GIB, seg*64, 255 - seg*64, 1, 64, 32.f);
      else
        k_gemm<<<dim3(BH, 6, 2), 256, 0, stream>>>(L1OUT, 512,
            (const f16*)nullptr, eWih + 2L*393216, 393216L, 512, 0, ebih + 1536, 768,
            GIB, gdir, 768, 2, seg*64, 255 - seg*64, 1, lbh, l1abstr, 32.f);
      k_enc_seg<<<nblk, 512, 0, stream>>>(GIB, eWhh + 2L*196608, ebhh + 1536,
                                          SEQ + (long)b0*512, 64,
                                          FIN + 65536 + (long)b0*512, HC, seg, BH);
    }
  }

  if (BH == 64) {
    f16* EP    = L1OUT;              // [64][256][512] f16 enc_proj (+attn_b), mode-3 layout
    f16* WIHSW = GIB + 3440640L;
    f16* WHSW  = GIB + 5799936L;

    k_prep_dec<<<2816, 256, 0, stream>>>(dWhh, attnW, fcconW, dWih, R3);
    k_gemm<<<dim3(256, 4, 1), 256, 0, stream>>>(SEQ, 512,
        R3 + 2359296L, (const float*)nullptr, 0L, 0, 0, attnB, 0,
        EP, 0L, 512, 3, 0, 0, 1, 6, 64, 32.f);
    k_dec_init<<<512, 256, 0, stream>>>(FIN, SEQ, HB, HF, CAT, CNT);

    for (int s = 0; s < 24; ++s) {
      const int p = s & 1;
      k_attn<<<64, 512, 0, stream>>>(SEQ, EP, HF + 2*32768, CAT, WHSW, R3 + 2621440L,
          fcconB, vW, INP, fcW, fcB, OUT, s);
      k_cell3<<<32, 256, 0, stream>>>(INP, WIHSW, R3, dbih, dbhh, HF, HB, CAT,
          p, CNT + s*128);
    }
    k_out<<<64, 256, 0, stream>>>(HF + 2*32768, fcW, fcB, OUT, 23);
  } else {
    k_prep_dec<<<1536, 256, 0, stream>>>(dWhh, attnW, fcconW, dWih, R3);
    k_dec_init<<<512, 256, 0, stream>>>(FIN, SEQ, HB, HF, CAT, (u32*)(S + 16000));

    for (int s = 0; s < 24; ++s) {
      const int p = s & 1;
      const f16* h2in = HB + (4 + p)*32768L;
      k_gemm<<<dim3(1,4,1), 256, 0, stream>>>(h2in, 512,
          (const f16*)nullptr, attnW, 0L, 1024, 0, (const float*)nullptr, 0,
          HQ, 0L, 512, 0, 0, 0, 0, 6, 64, 64.f);
      k_score<<<256, 256, 0, stream>>>(SEQ, R3 + 2359296L, HQ, attnB, vW, S);
      k_attnctx<<<64, 256, 0, stream>>>(S, SEQ, CAT);
      k_gemm<<<dim3(1,4,1), 256, 0, stream>>>(CAT, 1024,
          R3 + 2621440L, (const float*)nullptr, 0L, 0, 0, fcconB, 0,
          INP, 0L, 512, 1, 0, 0, 0, 6, 64, 64.f);
      for (int l = 0; l < 3; ++l) {
        const f16* inp = (l == 0) ? INP : (HB + (2*(l-1) + (1-p))*32768L);
        k_cell_raw<<<8, 256, 0, stream>>>(inp,
                  dWih + (long)l*786432, R3 + (long)l*786432,
                  dbih + l*1536, dbhh + l*1536, HF + (long)l*32768,
                  HB + (2*l + p)*32768L, HB + (2*l + (1-p))*32768L,
                  (l == 2) ? CAT : (f16*)nullptr);
      }
      k_out<<<64, 256, 0, stream>>>(HF + 2*32768, fcW, fcB, OUT, s);
    }
  }
}

// Round 12
// 5842.694 us; speedup vs baseline: 1.9452x; 1.0373x over previous
//
#include <hip/hip_runtime.h>

typedef unsigned short u16;
typedef unsigned int u32;
typedef _Float16 f16;
typedef f16   f16x2 __attribute__((ext_vector_type(2)));
typedef f16   f16x4 __attribute__((ext_vector_type(4)));
typedef f16   f16x8 __attribute__((ext_vector_type(8)));
typedef float f32x4 __attribute__((ext_vector_type(4)));

#define MFMA16(a,b,c) __builtin_amdgcn_mfma_f32_16x16x32_f16((a),(b),(c),0,0,0)

__device__ __forceinline__ float sigm_(float x){ return 1.f/(1.f + __expf(-x)); }
__device__ __forceinline__ float tanh_(float x){ return 1.f - 2.f/(1.f + __expf(2.f*x)); }
__device__ __forceinline__ float clampf(float x, float c){
  if (!(x > -c)) x = -c;
  if (x > c) x = c;
  return x;
}
__device__ __forceinline__ f16x8 cvt8f(const float* p){
  const float4 a = *(const float4*)p;
  const float4 b = *(const float4*)(p+4);
  f16x8 r;
  r[0]=(f16)a.x; r[1]=(f16)a.y; r[2]=(f16)a.z; r[3]=(f16)a.w;
  r[4]=(f16)b.x; r[5]=(f16)b.y; r[6]=(f16)b.z; r[7]=(f16)b.w;
  return r;
}

// narrow 8-member device barrier (per-mi-group); throttled spin, unique counter line
__device__ __forceinline__ void gbar8_(u32* c){
  __syncthreads();
  __threadfence();
  if (threadIdx.x == 0) {
    __hip_atomic_fetch_add(c, 1u, __ATOMIC_RELAXED, __HIP_MEMORY_SCOPE_AGENT);
    while (__hip_atomic_load(c, __ATOMIC_RELAXED, __HIP_MEMORY_SCOPE_AGENT) < 8u)
      __builtin_amdgcn_s_sleep(2);
  }
  __syncthreads();
  __threadfence();
}

// ---------- diagnostic ----------
__global__ void k_diag(float* out, int mib){
  const int i = blockIdx.x*256 + threadIdx.x;
  if (i < 3072) out[i] = 1000.f * (float)mib;
}

// ---------- decoder weight swizzle (fp32 -> f16 MFMA B-frags) ----------
__global__ void k_prep_dec(const float* dWhh, const float* attnW, const float* fccon,
                           const float* dWih, f16* R3)
{
  long idx = (long)blockIdx.x*256 + threadIdx.x;
  const float* src; int rs, colOff = 0, NKS; long dst, loc;
  if (idx < 294912L) {
    loc = idx; const int m = (int)(loc / 98304); loc %= 98304;
    src = dWhh + (long)m*786432; rs = 512; NKS = 16; dst = (long)m*786432;
  } else if (idx < 327680L) {
    loc = idx - 294912L; src = attnW; colOff = 512; rs = 1024; NKS = 16; dst = 2359296L;
  } else if (idx < 393216L) {
    loc = idx - 327680L; src = fccon; rs = 1024; NKS = 32; dst = 2621440L;
  } else if (idx < 688128L) {
    loc = idx - 393216L; const int m = (int)(loc / 98304); loc %= 98304;
    src = dWih + (long)m*786432; rs = 512; NKS = 16; dst = 3440640L + (long)m*786432;
  } else if (idx < 720896L) {
    loc = idx - 688128L; src = attnW; colOff = 0; rs = 1024; NKS = 16; dst = 5799936L;
  } else return;
  const int lane = (int)(loc & 63);
  const long frag = loc >> 6;
  const int ks = (int)(frag % NKS);
  const long nt = frag / NKS;
  const int n  = (int)(nt*16 + (lane & 15));
  const int k0 = ks*32 + ((lane >> 4) << 3);
  const float* sp = src + (long)n*rs + colOff + k0;
  f16* dp = R3 + dst + loc*8;
  #pragma unroll
  for (int j = 0; j < 8; ++j) dp[j] = (f16)sp[j];
}

// ---------- (half path) layer-0 gi, v2 layout ----------
__global__ void k_gi0s(const float* __restrict__ x, const float* __restrict__ W,
                       const float* __restrict__ bi, f16* __restrict__ gi,
                       int seg, int BH, int lbh, int b0)
{
  const long idx = (long)blockIdx.x*256 + threadIdx.x;
  const int v = (int)(idx % 24);
  long rest = idx / 24;
  const int tid = (int)(rest & 511); rest >>= 9;
  const int bq = (int)(rest & ((1 << (lbh-4)) - 1)); rest >>= (lbh-4);
  const int s = (int)(rest & 63);
  const int d = (int)(rest >> 6);
  const int r = v / 6, rem = v % 6, i = rem / 3, g = rem % 3;
  const int w = tid >> 6, q = (tid >> 4) & 3, lo = tid & 15;
  const int n = g*256 + (2*w + i)*16 + lo;
  const int b = bq*16 + q*4 + r;
  const int t = d ? (255 - (seg*64 + s)) : (seg*64 + s);
  const float x0 = x[(((b0+b)<<8) + t)*2];
  const float x1 = x[(((b0+b)<<8) + t)*2 + 1];
  const long wi = ((long)d*768 + n)*2;
  gi[idx] = (f16)clampf(x0*W[wi] + x1*W[wi+1] + bi[d*768 + n], 32.f);
}

// gi element accessor: 24 contiguous f16 held as 3 x f16x8
#define GIE(G, vv) ((float)((vv) < 8 ? (G)[0][(vv)&7] : ((vv) < 16 ? (G)[1][(vv)-8] : (G)[2][(vv)-16])))

// ---------- (half path) encoder recurrence: 512 thr / 8 waves, STEPS=64 ----------
__global__ __launch_bounds__(512, 1) void k_enc_seg(
    const f16* __restrict__ gi, const float* __restrict__ Wraw,
    const float* __restrict__ bhh, f16* __restrict__ seq, int ostr,
    f16* __restrict__ fin, float* __restrict__ hcar, int seg, int BH)
{
  const int tid = threadIdx.x;
  const int w = tid >> 6, lane = tid & 63;
  const int lo16 = lane & 15, quad = lane >> 4;
  const int nbq = BH >> 4;
  const int dir = blockIdx.x / nbq, bq = blockIdx.x % nbq;

  __shared__ f16 h16[4][16][264];

  const float* mat = Wraw + (long)dir*196608;
  f16x8 wr[6][8];
  #pragma unroll
  for (int p = 0; p < 3; ++p)
    #pragma unroll
    for (int i = 0; i < 2; ++i) {
      const int n = (p*16 + 2*w + i)*16 + lo16;
      #pragma unroll
      for (int ks = 0; ks < 8; ++ks)
        wr[p*2+i][ks] = cvt8f(mat + (long)n*256 + ks*32 + quad*8);
    }
  float bh_[3][2];
  #pragma unroll
  for (int p = 0; p < 3; ++p)
    #pragma unroll
    for (int i = 0; i < 2; ++i)
      bh_[p][i] = bhh[dir*768 + p*256 + (2*w+i)*16 + lo16];

  float hreg[2][4];
  if (seg == 0) {
    #pragma unroll
    for (int i = 0; i < 2; ++i)
      #pragma unroll
      for (int r = 0; r < 4; ++r) {
        hreg[i][r] = 0.f;
        h16[0][quad*4 + r][(2*w+i)*16 + lo16] = (f16)0.f;
      }
  } else {
    #pragma unroll
    for (int i = 0; i < 2; ++i) {
      const int c = (2*w+i)*16 + lo16;
      #pragma unroll
      for (int r = 0; r < 4; ++r) {
        const float v = hcar[((dir*BH) + bq*16 + quad*4 + r)*256 + c];
        hreg[i][r] = v;
        h16[0][quad*4 + r][c] = (f16)v;
      }
    }
  }

  const long gstep = (long)nbq*512*24;
  const f16* gbase = gi + (((long)dir*64*nbq + bq)*512 + tid)*24;
  f16x8 g0[3], g1[3];
  { const f16x8* gp = (const f16x8*)gbase; g0[0]=gp[0]; g0[1]=gp[1]; g0[2]=gp[2]; }

  const int frow = tid >> 5;
  const int fcol = (tid & 31) * 8;

  for (int s = 0; s < 64; ++s) {
    __syncthreads();
    if (s >= 2) {
      const int so = s - 2;
      const int t2 = dir ? (255 - (seg*64 + so)) : (seg*64 + so);
      const f16x8 hv = *(const f16x8*)&h16[(so+1)&3][frow][fcol];
      *(f16x8*)&seq[((long)t2*ostr + bq*16 + frow)*512 + dir*256 + fcol] = hv;
    }
    f32x4 acc[6];
    #pragma unroll
    for (int q = 0; q < 6; ++q) acc[q] = (f32x4){0.f,0.f,0.f,0.f};
    #pragma unroll
    for (int ks = 0; ks < 8; ++ks) {
      const f16x8 a = *(const f16x8*)&h16[s&3][lo16][ks*32 + quad*8];
      #pragma unroll
      for (int q = 0; q < 6; ++q)
        acc[q] = MFMA16(a, wr[q][ks], acc[q]);
    }
    if (s < 63) {
      const f16x8* gp = (const f16x8*)(gbase + (long)(s+1)*gstep);
      g1[0]=gp[0]; g1[1]=gp[1]; g1[2]=gp[2];
    }
    #pragma unroll
    for (int i = 0; i < 2; ++i) {
      const int c = (2*w+i)*16 + lo16;
      #pragma unroll
      for (int r = 0; r < 4; ++r) {
        const int row = quad*4 + r;
        const int v = r*6 + i*3;
        const float gir = GIE(g0, v);
        const float giz = GIE(g0, v+1);
        const float gin = GIE(g0, v+2);
        const float rv = sigm_(gir + acc[i][r]   + bh_[0][i]);
        const float zv = sigm_(giz + acc[2+i][r] + bh_[1][i]);
        const float nv = tanh_(gin + rv*(acc[4+i][r] + bh_[2][i]));
        float hn = (1.f - zv)*nv + zv*hreg[i][r];
        hn = clampf(hn, 2.f);
        hreg[i][r] = hn;
        h16[(s+1)&3][row][c] = (f16)hn;
        if (seg == 3 && s == 63) fin[(bq*16 + row)*512 + dir*256 + c] = (f16)hn;
      }
    }
    g0[0]=g1[0]; g0[1]=g1[1]; g0[2]=g1[2];
  }
  __syncthreads();
  #pragma unroll
  for (int so = 62; so < 64; ++so) {
    const int t2 = dir ? (255 - (seg*64 + so)) : (seg*64 + so);
    const f16x8 hv = *(const f16x8*)&h16[(so+1)&3][frow][fcol];
    *(f16x8*)&seq[((long)t2*ostr + bq*16 + frow)*512 + dir*256 + fcol] = hv;
  }
  #pragma unroll
  for (int i = 0; i < 2; ++i) {
    const int c = (2*w+i)*16 + lo16;
    #pragma unroll
    for (int r = 0; r < 4; ++r)
      hcar[((dir*BH) + bq*16 + quad*4 + r)*256 + c] = hreg[i][r];
  }
}

// ---------- big path: fused half-seg encoder + next-half gi producer ----------
// blocks [0, 8*encOn): enc (32 steps, BH=64); remaining blocks: producer for half ht.
// prodMode 1 = layer-0 gi from x (256 blocks); 2 = gi GEMM (128 blocks, 2 sub-blocks).
// No inter-block sync: producers write giP (other buffer); handoff at kernel boundary.
__global__ __launch_bounds__(512, 1) void k_enc_f(
    const f16* __restrict__ giC, f16* __restrict__ giP,
    const float* __restrict__ Wraw, const float* __restrict__ bhh,
    f16* __restrict__ seq, f16* __restrict__ fin, float* __restrict__ hcar,
    int hs, int encOn, int prodMode, int ht,
    const float* __restrict__ xin, const float* __restrict__ Wih0,
    const float* __restrict__ bih0,
    const f16* __restrict__ Asrc, const float* __restrict__ Braw,
    const float* __restrict__ bias)
{
  __shared__ f16 h16[4][16][264];
  const int tid = threadIdx.x;
  const int bid = blockIdx.x;

  if (encOn && bid < 8) {
    // ---- enc path: 32-step half-seg, dir = bid/4, bq = bid%4 ----
    const int w = tid >> 6, lane = tid & 63;
    const int lo16 = lane & 15, quad = lane >> 4;
    const int dir = bid >> 2, bq = bid & 3;

    const float* mat = Wraw + (long)dir*196608;
    f16x8 wr[6][8];
    #pragma unroll
    for (int p = 0; p < 3; ++p)
      #pragma unroll
      for (int i = 0; i < 2; ++i) {
        const int n = (p*16 + 2*w + i)*16 + lo16;
        #pragma unroll
        for (int ks = 0; ks < 8; ++ks)
          wr[p*2+i][ks] = cvt8f(mat + (long)n*256 + ks*32 + quad*8);
      }
    float bh_[3][2];
    #pragma unroll
    for (int p = 0; p < 3; ++p)
      #pragma unroll
      for (int i = 0; i < 2; ++i)
        bh_[p][i] = bhh[dir*768 + p*256 + (2*w+i)*16 + lo16];

    float hreg[2][4];
    if (hs == 0) {
      #pragma unroll
      for (int i = 0; i < 2; ++i)
        #pragma unroll
        for (int r = 0; r < 4; ++r) {
          hreg[i][r] = 0.f;
          h16[0][quad*4 + r][(2*w+i)*16 + lo16] = (f16)0.f;
        }
    } else {
      #pragma unroll
      for (int i = 0; i < 2; ++i) {
        const int c = (2*w+i)*16 + lo16;
        #pragma unroll
        for (int r = 0; r < 4; ++r) {
          const float v = hcar[((dir*64) + bq*16 + quad*4 + r)*256 + c];
          hreg[i][r] = v;
          h16[0][quad*4 + r][c] = (f16)v;
        }
      }
    }

    const long gstep = 4L*512*24;
    const f16* gbase = giC + (((long)dir*32*4 + bq)*512 + tid)*24;
    f16x8 g0[3], g1[3];
    { const f16x8* gp = (const f16x8*)gbase; g0[0]=gp[0]; g0[1]=gp[1]; g0[2]=gp[2]; }

    const int frow = tid >> 5;
    const int fcol = (tid & 31) * 8;

    for (int s = 0; s < 32; ++s) {
      __syncthreads();
      if (s >= 2) {
        const int so = s - 2;
        const int t2 = dir ? (255 - (hs*32 + so)) : (hs*32 + so);
        const f16x8 hv = *(const f16x8*)&h16[(so+1)&3][frow][fcol];
        *(f16x8*)&seq[((long)t2*64 + bq*16 + frow)*512 + dir*256 + fcol] = hv;
      }
      f32x4 acc[6];
      #pragma unroll
      for (int q = 0; q < 6; ++q) acc[q] = (f32x4){0.f,0.f,0.f,0.f};
      #pragma unroll
      for (int ks = 0; ks < 8; ++ks) {
        const f16x8 a = *(const f16x8*)&h16[s&3][lo16][ks*32 + quad*8];
        #pragma unroll
        for (int q = 0; q < 6; ++q)
          acc[q] = MFMA16(a, wr[q][ks], acc[q]);
      }
      if (s < 31) {
        const f16x8* gp = (const f16x8*)(gbase + (long)(s+1)*gstep);
        g1[0]=gp[0]; g1[1]=gp[1]; g1[2]=gp[2];
      }
      #pragma unroll
      for (int i = 0; i < 2; ++i) {
        const int c = (2*w+i)*16 + lo16;
        #pragma unroll
        for (int r = 0; r < 4; ++r) {
          const int row = quad*4 + r;
          const int v = r*6 + i*3;
          const float gir = GIE(g0, v);
          const float giz = GIE(g0, v+1);
          const float gin = GIE(g0, v+2);
          const float rv = sigm_(gir + acc[i][r]   + bh_[0][i]);
          const float zv = sigm_(giz + acc[2+i][r] + bh_[1][i]);
          const float nv = tanh_(gin + rv*(acc[4+i][r] + bh_[2][i]));
          float hn = (1.f - zv)*nv + zv*hreg[i][r];
          hn = clampf(hn, 2.f);
          hreg[i][r] = hn;
          h16[(s+1)&3][row][c] = (f16)hn;
          if (hs == 7 && s == 31) fin[(bq*16 + row)*512 + dir*256 + c] = (f16)hn;
        }
      }
      g0[0]=g1[0]; g0[1]=g1[1]; g0[2]=g1[2];
    }
    __syncthreads();
    #pragma unroll
    for (int so = 30; so < 32; ++so) {
      const int t2 = dir ? (255 - (hs*32 + so)) : (hs*32 + so);
      const f16x8 hv = *(const f16x8*)&h16[(so+1)&3][frow][fcol];
      *(f16x8*)&seq[((long)t2*64 + bq*16 + frow)*512 + dir*256 + fcol] = hv;
    }
    #pragma unroll
    for (int i = 0; i < 2; ++i) {
      const int c = (2*w+i)*16 + lo16;
      #pragma unroll
      for (int r = 0; r < 4; ++r)
        hcar[((dir*64) + bq*16 + quad*4 + r)*256 + c] = hreg[i][r];
    }
    return;
  }

  const int pb = bid - (encOn ? 8 : 0);
  if (prodMode == 1) {
    // ---- layer-0 gi producer for half ht: one 24-f16 record per thread ----
    const int u = pb*512 + tid;        // [0, 131072)
    const int tid9 = u & 511;
    const int bq = (u >> 9) & 3;
    const int s  = (u >> 11) & 31;
    const int d  = u >> 16;
    const int w = tid9 >> 6, q = (tid9 >> 4) & 3, lo = tid9 & 15;
    float wv0[2][3], wv1[2][3], bv[2][3];
    #pragma unroll
    for (int i = 0; i < 2; ++i)
      #pragma unroll
      for (int g = 0; g < 3; ++g) {
        const int n = g*256 + (2*w + i)*16 + lo;
        const long wi = ((long)d*768 + n)*2;
        wv0[i][g] = Wih0[wi];
        wv1[i][g] = Wih0[wi + 1];
        bv[i][g]  = bih0[d*768 + n];
      }
    f16x8 rec[3];
    #pragma unroll
    for (int r = 0; r < 4; ++r) {
      const int b = bq*16 + q*4 + r;
      const int t = d ? (255 - (ht*32 + s)) : (ht*32 + s);
      const float x0 = xin[((b<<8) + t)*2];
      const float x1 = xin[((b<<8) + t)*2 + 1];
      #pragma unroll
      for (int i = 0; i < 2; ++i)
        #pragma unroll
        for (int g = 0; g < 3; ++g) {
          const int slot = r*6 + i*3 + g;
          rec[slot>>3][slot&7] = (f16)clampf(x0*wv0[i][g] + x1*wv1[i][g] + bv[i][g], 32.f);
        }
    }
    f16* dp = giP + ((((long)d*32 + s)*4 + bq)*512 + tid9)*24;
    *(f16x8*)(dp)      = rec[0];
    *(f16x8*)(dp + 8)  = rec[1];
    *(f16x8*)(dp + 16) = rec[2];
  } else if (prodMode == 2) {
    // ---- gi GEMM producer for half ht (round-8 body, s-dim 32, 2 sub-blocks) ----
    const int s2 = pb & 15, y = (pb >> 4) & 3, z = pb >> 6;
    const int sub = tid >> 8, stid = tid & 255;
    const int s_ = s2*2 + sub;
    const int w4 = stid >> 6, lane = stid & 63;
    const int lo16 = lane & 15, quad = lane >> 4;
    const int tb = z ? (255 - ht*32) : (ht*32);
    const int td = z ? -1 : 1;
    const long arow = (long)(tb + td*s_)*64 + (w4*16 + lo16);
    const f16* Ap = Asrc + arow*512 + quad*8;
    const float* Bp = Braw + (long)z*393216;
    f32x4 acc[12];
    #pragma unroll
    for (int i=0;i<12;++i) acc[i]=(f32x4){0.f,0.f,0.f,0.f};
    for (int ks = 0; ks < 16; ++ks) {
      const f16x8 a = *(const f16x8*)(Ap + ks*32);
      #pragma unroll
      for (int g = 0; g < 3; ++g)
        #pragma unroll
        for (int jj = 0; jj < 4; ++jj) {
          const int n = g*256 + y*64 + jj*16 + lo16;
          const f16x8 b = cvt8f(Bp + (long)n*512 + ks*32 + quad*8);
          acc[g*4+jj] = MFMA16(a, b, acc[g*4+jj]);
        }
    }
    f16* base = giP + (((long)z*32 + s_)*4 + w4)*12288L;
    #pragma unroll
    for (int l = 0; l < 2; ++l) {
      f16x8 rec8[3];
      #pragma unroll
      for (int r = 0; r < 4; ++r)
        #pragma unroll
        for (int jl = 0; jl < 2; ++jl)
          #pragma unroll
          for (int g = 0; g < 3; ++g) {
            const int nt = g*4 + l*2 + jl;
            const int n = g*256 + y*64 + (l*2+jl)*16 + lo16;
            const int slot = r*6 + jl*3 + g;
            rec8[slot>>3][slot&7] = (f16)clampf(acc[nt][r] + bias[z*768 + n], 32.f);
          }
      f16* dp = base + ((long)(y*2 + l)*64 + quad*16 + lo16)*24L;
      *(f16x8*)(dp)      = rec8[0];
      *(f16x8*)(dp + 8)  = rec8[1];
      *(f16x8*)(dp + 16) = rec8[2];
    }
  }
}

// ---------- MFMA GEMM; mode 0=f32 C, 1=f16 C, 2=f16 C gi-v2, 3=f16 C [b][t] transposed ----------
__global__ void k_gemm(const f16* __restrict__ A, int K,
                       const f16* __restrict__ Bsw, const float* __restrict__ Braw,
                       long bzs, int ldb, int koff,
                       const float* __restrict__ bias, int biaszs,
                       void* __restrict__ Cv, long czs, int ldc, int mode,
                       int tb0, int tb1, int tdirsgn, int lbh, int abstr, float cv)
{
  const int tid = threadIdx.x, w = tid>>6, lane = tid&63;
  const int lo16 = lane&15, quad = lane>>4;
  const int m0 = blockIdx.x*64 + w*16;
  const int n0 = blockIdx.y*128;
  const int z  = blockIdx.z;
  const int tbase = z ? tb1 : tb0;
  const int tdir  = z ? -tdirsgn : tdirsgn;
  const int NKS = K >> 5;
  const int mrow = m0 + lo16;
  const long arow = (long)(tbase + tdir*(mrow >> lbh))*abstr + (mrow & ((1<<lbh)-1));
  const f16* Ap = A + arow*K + quad*8;
  f32x4 acc[8];
  #pragma unroll
  for (int i=0;i<8;++i) acc[i]=(f32x4){0.f,0.f,0.f,0.f};
  if (Bsw) {
    const f16* Bp = Bsw + (long)z*bzs;
    for (int ks = 0; ks < NKS; ++ks) {
      const f16x8 a = *(const f16x8*)(Ap + ks*32);
      #pragma unroll
      for (int nt = 0; nt < 8; ++nt) {
        const f16x8 b = *(const f16x8*)(Bp + (((long)((n0>>4)+nt)*NKS + ks) << 9) + lane*8);
        acc[nt] = MFMA16(a, b, acc[nt]);
      }
    }
  } else {
    const float* Bp = Braw + (long)z*bzs;
    for (int ks = 0; ks < NKS; ++ks) {
      const f16x8 a = *(const f16x8*)(Ap + ks*32);
      #pragma unroll
      for (int nt = 0; nt < 8; ++nt) {
        const f16x8 b = cvt8f(Bp + (long)(n0 + nt*16 + lo16)*ldb + koff + ks*32 + quad*8);
        acc[nt] = MFMA16(a, b, acc[nt]);
      }
    }
  }
  #pragma unroll
  for (int nt = 0; nt < 8; ++nt) {
    const int n = n0 + nt*16 + lo16;
    const float bv = bias ? bias[z*biaszs + n] : 0.f;
    #pragma unroll
    for (int r = 0; r < 4; ++r) {
      const int m = m0 + quad*4 + r;
      const float val = clampf(acc[nt][r] + bv, cv);
      if (mode == 2) {
        const int s_ = m >> lbh, b_ = m & ((1<<lbh)-1);
        const int bq_ = b_ >> 4, q_ = (b_ >> 2) & 3, r_ = b_ & 3;
        const int g_ = n >> 8, j_ = (n >> 4) & 15, lo_ = n & 15;
        const long idx = ((((long)z*64 + s_)*(1<<(lbh-4)) + bq_)*512
                          + ((j_>>1)*64 + q_*16 + lo_))*24 + r_*6 + (j_&1)*3 + g_;
        ((f16*)Cv)[idx] = (f16)val;
      } else if (mode == 3)
        ((f16*)Cv)[(((long)(m & 63) << 8) + (m >> 6))*512 + n] = (f16)val;
      else if (mode == 1)
        ((f16*)Cv)[(long)z*czs + (long)m*ldc + n] = (f16)val;
      else
        ((float*)Cv)[(long)z*czs + (long)m*ldc + n] = val;
    }
  }
}

// ---------- (half path only) fused proj+score ----------
__global__ void k_score(const f16* __restrict__ seq, const f16* __restrict__ We,
                        const float* __restrict__ hq, const float* __restrict__ ab,
                        const float* __restrict__ vp, float* __restrict__ S)
{
  const int t = blockIdx.x, tid = threadIdx.x;
  const int w = tid>>6, lane = tid&63, lo16 = lane&15, quad = lane>>4;
  __shared__ float svab[1024];
  for (int i = tid; i < 512; i += 256) { svab[i] = vp[i]; svab[512+i] = ab[i]; }
  __syncthreads();
  f32x4 acc[32];
  #pragma unroll
  for (int i=0;i<32;++i) acc[i]=(f32x4){0.f,0.f,0.f,0.f};
  const f16* Ap = seq + ((long)t*64 + w*16 + lo16)*512 + quad*8;
  for (int ks = 0; ks < 16; ++ks) {
    const f16x8 a = *(const f16x8*)(Ap + ks*32);
    #pragma unroll
    for (int nt = 0; nt < 32; ++nt) {
      const f16x8 b = *(const f16x8*)(We + (((long)nt*16 + ks) << 9) + lane*8);
      acc[nt] = MFMA16(a, b, acc[nt]);
    }
  }
  #pragma unroll
  for (int r = 0; r < 4; ++r) {
    const int b = w*16 + quad*4 + r;
    float sc = 0.f;
    #pragma unroll
    for (int nt = 0; nt < 32; ++nt) {
      const int n = nt*16 + lo16;
      sc += svab[n] * tanh_(acc[nt][r] + hq[(b<<9) + n] + svab[512+n]);
    }
    sc += __shfl_xor(sc, 1, 64); sc += __shfl_xor(sc, 2, 64);
    sc += __shfl_xor(sc, 4, 64); sc += __shfl_xor(sc, 8, 64);
    if (lo16 == 0) S[(b<<8) + t] = clampf(sc, 256.f);
  }
}

// ---------- (half path only) softmax + context ----------
__global__ void k_attnctx(const float* __restrict__ S, const f16* __restrict__ enc,
                          f16* __restrict__ cat)
{
  const int b = blockIdx.x, tid = threadIdx.x;
  __shared__ float ssc[256], srd[256];
  const float sc = clampf(S[(b<<8) + tid], 256.f);
  srd[tid] = sc; __syncthreads();
  for (int off = 128; off > 0; off >>= 1) { if (tid < off) srd[tid] = fmaxf(srd[tid], srd[tid+off]); __syncthreads(); }
  const float mx = srd[0]; __syncthreads();
  const float e = __expf(sc - mx);
  srd[tid] = e; __syncthreads();
  for (int off = 128; off > 0; off >>= 1) { if (tid < off) srd[tid] += srd[tid+off]; __syncthreads(); }
  const float inv = 1.f / srd[0]; __syncthreads();
  ssc[tid] = e * inv; __syncthreads();
  float c0 = 0.f, c1 = 0.f;
  for (int tt = 0; tt < 256; ++tt) {
    const float awt = ssc[tt];
    const f16* ep = enc + (((long)tt*64 + b) << 9);
    c0 += awt * (float)ep[tid];
    c1 += awt * (float)ep[256 + tid];
  }
  cat[(b<<10) + 512 + tid] = (f16)clampf(c0, 4.f);
  cat[(b<<10) + 768 + tid] = (f16)clampf(c1, 4.f);
}

// ---------- decoder init (also zeroes barrier counters) ----------
__global__ void k_dec_init(const f16* __restrict__ fin, const f16* __restrict__ seq,
                           f16* __restrict__ hb16, float* __restrict__ hf32,
                           f16* __restrict__ cat, u32* __restrict__ cnt)
{
  const int idx = blockIdx.x*256 + threadIdx.x;
  if (idx < 3072) cnt[idx] = 0;
  const int d = idx & 511, b = (idx >> 9) & 63, l = idx >> 15;
  if (l < 3) {
    const float v = clampf((float)fin[((long)l<<15) + (b<<9) + d], 2.f);
    hb16[(long)l*65536 + (b<<9) + d] = (f16)v;
    hf32[(long)l*32768 + (b<<9) + d] = v;
  } else {
    cat[(b<<10) + d] = seq[((long)255*64 + b)*512 + d];
  }
}

// ---------- fused attention step (big path); ep in [b][t][512] layout ----------
__global__ __launch_bounds__(512, 1) void k_attn(
    const f16* __restrict__ seq, const f16* __restrict__ ep,
    const float* __restrict__ hf2, const f16* __restrict__ cat,
    const f16* __restrict__ whsw, const f16* __restrict__ fcsw,
    const float* __restrict__ fcconB, const float* __restrict__ vp,
    f16* __restrict__ inp, const float* __restrict__ fcW,
    const float* __restrict__ fcb, float* __restrict__ out, int step)
{
  const int b = blockIdx.x;
  const int tid = threadIdx.x, w = tid >> 6, lane = tid & 63;
  const int quad = lane >> 4;
  __shared__ float hsm[512];
  __shared__ float cats[1024];
  __shared__ float hqs[512];
  __shared__ float aw[256];
  __shared__ float red[8*512];
  hsm[tid]  = hf2[(b<<9) + tid];
  cats[tid] = (float)cat[(b<<10) + tid];
  __syncthreads();
  if (w < 2 && step > 0) {
    float p = 0.f;
    #pragma unroll
    for (int j = 0; j < 8; ++j) p += fcW[(w<<9) + lane*8 + j] * hsm[lane*8 + j];
    p += __shfl_xor(p,1,64); p += __shfl_xor(p,2,64); p += __shfl_xor(p,4,64);
    p += __shfl_xor(p,8,64); p += __shfl_xor(p,16,64); p += __shfl_xor(p,32,64);
    if (lane == 0) out[(b*24 + step-1)*2 + w] = clampf(p + fcb[w], 128.f);
  }
  #pragma unroll
  for (int i = 0; i < 4; ++i) {
    const int nt = w*4 + i;
    float p = 0.f;
    for (int ks = 0; ks < 16; ++ks) {
      const f16x8 wv = *(const f16x8*)(whsw + (((long)nt*16 + ks)<<9) + lane*8);
      const float4 ha = *(const float4*)&hsm[ks*32 + quad*8];
      const float4 hb = *(const float4*)&hsm[ks*32 + quad*8 + 4];
      p += (float)wv[0]*ha.x + (float)wv[1]*ha.y + (float)wv[2]*ha.z + (float)wv[3]*ha.w
         + (float)wv[4]*hb.x + (float)wv[5]*hb.y + (float)wv[6]*hb.z + (float)wv[7]*hb.w;
    }
    p += __shfl_xor(p,16,64); p += __shfl_xor(p,32,64);
    if (lane < 16) hqs[nt*16 + lane] = p;
  }
  __syncthreads();
  float hq8[8], v8[8];
  #pragma unroll
  for (int j = 0; j < 8; ++j) { hq8[j] = hqs[lane*8+j]; v8[j] = vp[lane*8+j]; }
  #pragma unroll 2
  for (int i = 0; i < 32; ++i) {
    const int t = w*32 + i;
    const f16x8 e = *(const f16x8*)(ep + (((long)(b<<8) + t)<<9) + lane*8);
    float s = 0.f;
    #pragma unroll
    for (int j = 0; j < 8; ++j) s += v8[j]*tanh_((float)e[j] + hq8[j]);
    s += __shfl_xor(s,1,64); s += __shfl_xor(s,2,64); s += __shfl_xor(s,4,64);
    s += __shfl_xor(s,8,64); s += __shfl_xor(s,16,64); s += __shfl_xor(s,32,64);
    if (lane == 0) aw[t] = clampf(s, 256.f);
  }
  __syncthreads();
  if (tid < 64) {
    float s0=aw[tid], s1=aw[tid+64], s2=aw[tid+128], s3=aw[tid+192];
    float mx = fmaxf(fmaxf(s0,s1), fmaxf(s2,s3));
    mx = fmaxf(mx, __shfl_xor(mx,1,64)); mx = fmaxf(mx, __shfl_xor(mx,2,64));
    mx = fmaxf(mx, __shfl_xor(mx,4,64)); mx = fmaxf(mx, __shfl_xor(mx,8,64));
    mx = fmaxf(mx, __shfl_xor(mx,16,64)); mx = fmaxf(mx, __shfl_xor(mx,32,64));
    const float e0=__expf(s0-mx), e1=__expf(s1-mx), e2=__expf(s2-mx), e3=__expf(s3-mx);
    float sm = e0+e1+e2+e3;
    sm += __shfl_xor(sm,1,64); sm += __shfl_xor(sm,2,64); sm += __shfl_xor(sm,4,64);
    sm += __shfl_xor(sm,8,64); sm += __shfl_xor(sm,16,64); sm += __shfl_xor(sm,32,64);
    const float inv = 1.f/sm;
    aw[tid]=e0*inv; aw[tid+64]=e1*inv; aw[tid+128]=e2*inv; aw[tid+192]=e3*inv;
  }
  __syncthreads();
  float c8[8];
  #pragma unroll
  for (int j = 0; j < 8; ++j) c8[j] = 0.f;
  #pragma unroll 2
  for (int i = 0; i < 32; ++i) {
    const int t = w*32 + i;
    const f16x8 e = *(const f16x8*)(seq + (((long)t*64 + b)<<9) + lane*8);
    const float awt = aw[t];
    #pragma unroll
    for (int j = 0; j < 8; ++j) c8[j] += awt*(float)e[j];
  }
  #pragma unroll
  for (int j = 0; j < 8; ++j) red[(w<<9) + lane*8 + j] = c8[j];
  __syncthreads();
  {
    float s = 0.f;
    #pragma unroll
    for (int ww = 0; ww < 8; ++ww) s += red[(ww<<9) + tid];
    cats[512 + tid] = clampf(s, 4.f);
  }
  __syncthreads();
  #pragma unroll
  for (int i = 0; i < 4; ++i) {
    const int nt = w*4 + i;
    float p = 0.f;
    for (int ks = 0; ks < 32; ++ks) {
      const f16x8 wv = *(const f16x8*)(fcsw + (((long)nt*32 + ks)<<9) + lane*8);
      const float4 ca = *(const float4*)&cats[ks*32 + quad*8];
      const float4 cb = *(const float4*)&cats[ks*32 + quad*8 + 4];
      p += (float)wv[0]*ca.x + (float)wv[1]*ca.y + (float)wv[2]*ca.z + (float)wv[3]*ca.w
         + (float)wv[4]*cb.x + (float)wv[5]*cb.y + (float)wv[6]*cb.z + (float)wv[7]*cb.w;
    }
    p += __shfl_xor(p,16,64); p += __shfl_xor(p,32,64);
    if (lane < 16) inp[(b<<9) + nt*16 + lane] = (f16)clampf(p + fcconB[nt*16+lane], 64.f);
  }
}

// ---------- fused 3-layer decoder GRU (big path): 32 blocks, per-mi-group 8-member barriers ----------
__global__ void k_cell3(const f16* __restrict__ inp0, const f16* __restrict__ WihSw,
                        const f16* __restrict__ WhhSw, const float* __restrict__ bihA,
                        const float* __restrict__ bhhA, float* __restrict__ hfA,
                        f16* __restrict__ hb, f16* __restrict__ cat, int p, u32* cnt)
{
  const int tid = threadIdx.x, w = tid>>6, lane = tid&63;
  const int lo16 = lane&15, quad = lane>>4;
  const int Wt = ((int)blockIdx.x & 7)*4 + w;     // 0..31
  const int mi = (int)blockIdx.x >> 3;            // 0..3 (16 rows each)
  for (int l = 0; l < 3; ++l) {
    const f16* inp = (l == 0) ? inp0 : (hb + (long)(2*(l-1) + (1-p))*32768);
    const f16* WihL = WihSw + (long)l*786432;
    const f16* WhhL = WhhSw + (long)l*786432;
    const float* bih = bihA + l*1536;
    const float* bhh = bhhA + l*1536;
    float* hf32 = hfA + (long)l*32768;
    const f16* hin = hb + (long)(2*l + p)*32768;
    f16* hout = hb + (long)(2*l + (1-p))*32768;
    f16* catp = (l == 2) ? cat : (f16*)nullptr;

    f32x4 arz[2], an_[2];
    #pragma unroll
    for (int i=0;i<2;++i){ arz[i]=(f32x4){0.f,0.f,0.f,0.f}; an_[i]=(f32x4){0.f,0.f,0.f,0.f}; }
    #pragma unroll 4
    for (int kk = 0; kk < 16; ++kk) {
      const f16x8 b0 = *(const f16x8*)(WihL + (((long)Wt*16 + kk)<<9)      + lane*8);
      const f16x8 b1 = *(const f16x8*)(WihL + (((long)(32+Wt)*16 + kk)<<9) + lane*8);
      const f16x8 b2 = *(const f16x8*)(WihL + (((long)(64+Wt)*16 + kk)<<9) + lane*8);
      const f16x8 a = *(const f16x8*)&inp[((mi*16 + lo16)<<9) + kk*32 + quad*8];
      arz[0] = MFMA16(a, b0, arz[0]);
      arz[1] = MFMA16(a, b1, arz[1]);
      an_[0] = MFMA16(a, b2, an_[0]);
    }
    #pragma unroll 4
    for (int kk = 0; kk < 16; ++kk) {
      const f16x8 b0 = *(const f16x8*)(WhhL + (((long)Wt*16 + kk)<<9)      + lane*8);
      const f16x8 b1 = *(const f16x8*)(WhhL + (((long)(32+Wt)*16 + kk)<<9) + lane*8);
      const f16x8 b2 = *(const f16x8*)(WhhL + (((long)(64+Wt)*16 + kk)<<9) + lane*8);
      const f16x8 a = *(const f16x8*)&hin[((mi*16 + lo16)<<9) + kk*32 + quad*8];
      arz[0] = MFMA16(a, b0, arz[0]);
      arz[1] = MFMA16(a, b1, arz[1]);
      an_[1] = MFMA16(a, b2, an_[1]);
    }
    const int c = Wt*16 + lo16;
    const float brz0 = bih[c]     + bhh[c];
    const float brz1 = bih[512+c] + bhh[512+c];
    const float bin_ = bih[1024+c];
    const float bhn_ = bhh[1024+c];
    #pragma unroll
    for (int r = 0; r < 4; ++r) {
      const int row = mi*16 + quad*4 + r;
      const float rv = sigm_(clampf(arz[0][r],64.f) + brz0);
      const float zv = sigm_(clampf(arz[1][r],64.f) + brz1);
      const float nv = tanh_(clampf(an_[0][r],64.f) + bin_ + rv*(clampf(an_[1][r],64.f) + bhn_));
      const float ho = hf32[(row<<9) + c];
      float hn2 = (1.f - zv)*nv + zv*ho;
      hn2 = clampf(hn2, 2.f);
      hf32[(row<<9) + c] = hn2;
      hout[(row<<9) + c] = (f16)hn2;
      if (catp) catp[(row<<10) + c] = (f16)hn2;
    }
    if (l < 2) gbar8_(cnt + (l*4 + mi)*16);
  }
}

// ---------- (half path only) original raw-Wih cell ----------
__global__ void k_cell_raw(const f16* __restrict__ inp, const float* __restrict__ WihRaw,
                           const f16* __restrict__ WhhSw, const float* __restrict__ bih,
                           const float* __restrict__ bhh, float* __restrict__ hf32,
                           const f16* __restrict__ hin, f16* __restrict__ hout,
                           f16* __restrict__ cat)
{
  const int tid = threadIdx.x, w = tid>>6, lane = tid&63;
  const int lo16 = lane&15, quad = lane>>4;
  const int Wt = blockIdx.x*4 + w;
  f32x4 arz[8], an_[8];
  #pragma unroll
  for (int i=0;i<8;++i){ arz[i]=(f32x4){0.f,0.f,0.f,0.f}; an_[i]=(f32x4){0.f,0.f,0.f,0.f}; }
  const int nr = Wt*16 + lo16;
  const float* Rr = WihRaw + (long)nr*512        + quad*8;
  const float* Rz = WihRaw + (long)(512+nr)*512  + quad*8;
  const float* Rn = WihRaw + (long)(1024+nr)*512 + quad*8;
  #pragma unroll 2
  for (int kk = 0; kk < 16; ++kk) {
    const f16x8 b0 = cvt8f(Rr + kk*32);
    const f16x8 b1 = cvt8f(Rz + kk*32);
    const f16x8 b2 = cvt8f(Rn + kk*32);
    #pragma unroll
    for (int mi = 0; mi < 4; ++mi) {
      const f16x8 a = *(const f16x8*)&inp[((mi*16 + lo16)<<9) + kk*32 + quad*8];
      arz[mi]   = MFMA16(a, b0, arz[mi]);
      arz[4+mi] = MFMA16(a, b1, arz[4+mi]);
      an_[mi]   = MFMA16(a, b2, an_[mi]);
    }
  }
  #pragma unroll 2
  for (int kk = 0; kk < 16; ++kk) {
    const f16x8 b0 = *(const f16x8*)(WhhSw + (((long)Wt*16 + kk)<<9)      + lane*8);
    const f16x8 b1 = *(const f16x8*)(WhhSw + (((long)(32+Wt)*16 + kk)<<9) + lane*8);
    const f16x8 b2 = *(const f16x8*)(WhhSw + (((long)(64+Wt)*16 + kk)<<9) + lane*8);
    #pragma unroll
    for (int mi = 0; mi < 4; ++mi) {
      const f16x8 a = *(const f16x8*)&hin[((mi*16 + lo16)<<9) + kk*32 + quad*8];
      arz[mi]   = MFMA16(a, b0, arz[mi]);
      arz[4+mi] = MFMA16(a, b1, arz[4+mi]);
      an_[4+mi] = MFMA16(a, b2, an_[4+mi]);
    }
  }
  const int c = Wt*16 + lo16;
  const float brz0 = bih[c]     + bhh[c];
  const float brz1 = bih[512+c] + bhh[512+c];
  const float bin_ = bih[1024+c];
  const float bhn_ = bhh[1024+c];
  #pragma unroll
  for (int mi = 0; mi < 4; ++mi)
    #pragma unroll
    for (int r = 0; r < 4; ++r) {
      const int row = mi*16 + quad*4 + r;
      const float rv = sigm_(clampf(arz[mi][r],64.f)   + brz0);
      const float zv = sigm_(clampf(arz[4+mi][r],64.f) + brz1);
      const float nv = tanh_(clampf(an_[mi][r],64.f) + bin_ + rv*(clampf(an_[4+mi][r],64.f) + bhn_));
      const float ho = hf32[(row<<9) + c];
      float hn2 = (1.f - zv)*nv + zv*ho;
      hn2 = clampf(hn2, 2.f);
      hf32[(row<<9) + c] = hn2;
      hout[(row<<9) + c] = (f16)hn2;
      if (cat) cat[(row<<10) + c] = (f16)hn2;
    }
}

// ---------- final projection ----------
__global__ void k_out(const float* __restrict__ h2, const float* __restrict__ fcW,
                      const float* __restrict__ fcb, float* __restrict__ out, int step)
{
  const int b = blockIdx.x, t = threadIdx.x;
  __shared__ float r0[256], r1[256];
  const float ha = clampf(h2[(b<<9) + t], 2.f);
  const float hb = clampf(h2[(b<<9) + 256 + t], 2.f);
  r0[t] = ha*fcW[t]     + hb*fcW[256+t];
  r1[t] = ha*fcW[512+t] + hb*fcW[768+t];
  __syncthreads();
  for (int off = 128; off > 0; off >>= 1) {
    if (t < off) { r0[t] += r0[t+off]; r1[t] += r1[t+off]; }
    __syncthreads();
  }
  if (t == 0) {
    out[(b*24 + step)*2]     = clampf(r0[0] + fcb[0], 128.f);
    out[(b*24 + step)*2 + 1] = clampf(r1[0] + fcb[1], 128.f);
  }
}

extern "C" void kernel_launch(void* const* d_in, const int* in_sizes, int n_in,
                              void* d_out, int out_size, void* d_ws, size_t ws_size,
                              hipStream_t stream) {
  const float* X      = (const float*)d_in[0];
  const float* eWih0  = (const float*)d_in[1];
  const float* eWhh0  = (const float*)d_in[2];
  const float* ebih0  = (const float*)d_in[3];
  const float* ebhh0  = (const float*)d_in[4];
  const float* eWih   = (const float*)d_in[5];
  const float* eWhh   = (const float*)d_in[6];
  const float* ebih   = (const float*)d_in[7];
  const float* ebhh   = (const float*)d_in[8];
  const float* dWih   = (const float*)d_in[9];
  const float* dWhh   = (const float*)d_in[10];
  const float* dbih   = (const float*)d_in[11];
  const float* dbhh   = (const float*)d_in[12];
  const float* fcconW = (const float*)d_in[13];
  const float* fcconB = (const float*)d_in[14];
  const float* attnW  = (const float*)d_in[15];
  const float* attnB  = (const float*)d_in[16];
  const float* vW     = (const float*)d_in[17];
  const float* fcW    = (const float*)d_in[18];
  const float* fcB    = (const float*)d_in[19];
  float* OUT = (float*)d_out;

  const long need_big  = 47054848L;
  const long need_half = 32964608L;
  f16* H = (f16*)d_ws;
  f16 *SEQ = H, *L1OUT, *GIB, *R3, *FIN, *HB, *CAT, *INP;
  float *HC;
  int BH, lbh, nh, l1ostr, l1abstr; long gdir;

  if ((long)ws_size >= need_big) {
    BH = 64; lbh = 6; nh = 1; l1ostr = 64; l1abstr = 64;
    L1OUT = H + 8388608L;
    GIB   = H + 16777216L;
    HC    = (float*)(H + 23068672L);
    FIN   = H + 23134208L;
    HB    = H + 23232512L;
    CAT   = H + 23429120L;
    INP   = H + 23494656L;
    gdir  = 3145728L;
  } else if ((long)ws_size >= need_half) {
    BH = 32; lbh = 5; nh = 2; l1ostr = 32; l1abstr = 32;
    L1OUT = H + 8388608L;
    GIB   = H + 12582912L;
    HC    = (float*)(H + 16023552L);
    FIN   = H + 16089088L;
    HB    = H + 16187392L;
    CAT   = H + 16384000L;
    INP   = H + 16449536L;
    gdir  = 1572864L;
  } else {
    k_diag<<<12, 256, 0, stream>>>(OUT, (int)(ws_size >> 20));
    return;
  }
  R3 = GIB;
  float* ST = (float*)(GIB + 3145728L);
  float* HQ = ST;
  float* HF = ST + 32768;
  float* S  = ST + 131072;
  u32* CNT = (u32*)ST;              // big path only (HQ unused there)
  const int nblk = 2*(BH>>4);

  if (BH == 64) {
    // ---- big path encoder: half-seg pipeline, gi double-buffered in GIB ----
    f16* GI[2] = { GIB, GIB + 3145728L };
    // layer 0
    k_enc_f<<<256, 512, 0, stream>>>(GI[0], GI[0], eWhh0, ebhh0, SEQ, FIN, HC,
        0, 0, 1, 0, X, eWih0, ebih0, (const f16*)nullptr, (const float*)nullptr,
        (const float*)nullptr);
    for (int h = 0; h < 8; ++h) {
      const int prod = (h < 7) ? 1 : 0;
      k_enc_f<<<8 + (prod ? 256 : 0), 512, 0, stream>>>(GI[h&1], GI[(h+1)&1],
          eWhh0, ebhh0, SEQ, FIN, HC, h, 1, prod, h+1, X, eWih0, ebih0,
          (const f16*)nullptr, (const float*)nullptr, (const float*)nullptr);
    }
    // layer 1
    k_enc_f<<<128, 512, 0, stream>>>(GI[0], GI[0], eWhh, ebhh, L1OUT, FIN + 32768, HC,
        0, 0, 2, 0, (const float*)nullptr, (const float*)nullptr, (const float*)nullptr,
        SEQ, eWih, ebih);
    for (int h = 0; h < 8; ++h) {
      const int prod = (h < 7) ? 2 : 0;
      k_enc_f<<<8 + (prod ? 128 : 0), 512, 0, stream>>>(GI[h&1], GI[(h+1)&1],
          eWhh, ebhh, L1OUT, FIN + 32768, HC, h, 1, prod, h+1,
          (const float*)nullptr, (const float*)nullptr, (const float*)nullptr,
          SEQ, eWih, ebih);
    }
    // layer 2
    k_enc_f<<<128, 512, 0, stream>>>(GI[0], GI[0], eWhh + 2L*196608, ebhh + 1536,
        SEQ, FIN + 65536, HC, 0, 0, 2, 0,
        (const float*)nullptr, (const float*)nullptr, (const float*)nullptr,
        L1OUT, eWih + 2L*393216, ebih + 1536);
    for (int h = 0; h < 8; ++h) {
      const int prod = (h < 7) ? 2 : 0;
      k_enc_f<<<8 + (prod ? 128 : 0), 512, 0, stream>>>(GI[h&1], GI[(h+1)&1],
          eWhh + 2L*196608, ebhh + 1536, SEQ, FIN + 65536, HC, h, 1, prod, h+1,
          (const float*)nullptr, (const float*)nullptr, (const float*)nullptr,
          L1OUT, eWih + 2L*393216, ebih + 1536);
    }

    // ---- big path decoder (round-11 proven) ----
    f16* EP    = L1OUT;              // [64][256][512] f16 enc_proj (+attn_b), mode-3 layout
    f16* WIHSW = GIB + 3440640L;
    f16* WHSW  = GIB + 5799936L;

    k_prep_dec<<<2816, 256, 0, stream>>>(dWhh, attnW, fcconW, dWih, R3);
    k_gemm<<<dim3(256, 4, 1), 256, 0, stream>>>(SEQ, 512,
        R3 + 2359296L, (const float*)nullptr, 0L, 0, 0, attnB, 0,
        EP, 0L, 512, 3, 0, 0, 1, 6, 64, 32.f);
    k_dec_init<<<512, 256, 0, stream>>>(FIN, SEQ, HB, HF, CAT, CNT);

    for (int s = 0; s < 24; ++s) {
      const int p = s & 1;
      k_attn<<<64, 512, 0, stream>>>(SEQ, EP, HF + 2*32768, CAT, WHSW, R3 + 2621440L,
          fcconB, vW, INP, fcW, fcB, OUT, s);
      k_cell3<<<32, 256, 0, stream>>>(INP, WIHSW, R3, dbih, dbhh, HF, HB, CAT,
          p, CNT + s*128);
    }
    k_out<<<64, 256, 0, stream>>>(HF + 2*32768, fcW, fcB, OUT, 23);
  } else {
    // ---- half path (unchanged) ----
    const int gi0grid = (2*64*BH*768)/256;
    for (int h = 0; h < nh; ++h) {
      const int b0 = h*BH;
      for (int seg = 0; seg < 4; ++seg) {
        k_gi0s<<<gi0grid, 256, 0, stream>>>(X, eWih0, ebih0, GIB, seg, BH, lbh, b0);
        k_enc_seg<<<nblk, 512, 0, stream>>>(GIB, eWhh0, ebhh0, SEQ + (long)b0*512, 64,
                                            FIN + (long)b0*512, HC, seg, BH);
      }
      for (int seg = 0; seg < 4; ++seg) {
        k_gemm<<<dim3(BH, 6, 2), 256, 0, stream>>>(SEQ + (long)b0*512, 512,
            (const f16*)nullptr, eWih, 393216L, 512, 0, ebih, 768,
            GIB, gdir, 768, 2, seg*64, 255 - seg*64, 1, lbh, 64, 32.f);
        k_enc_seg<<<nblk, 512, 0, stream>>>(GIB, eWhh, ebhh, L1OUT, l1ostr,
                                            FIN + 32768 + (long)b0*512, HC, seg, BH);
      }
      for (int seg = 0; seg < 4; ++seg) {
        k_gemm<<<dim3(BH, 6, 2), 256, 0, stream>>>(L1OUT, 512,
            (const f16*)nullptr, eWih + 2L*393216, 393216L, 512, 0, ebih + 1536, 768,
            GIB, gdir, 768, 2, seg*64, 255 - seg*64, 1, lbh, l1abstr, 32.f);
        k_enc_seg<<<nblk, 512, 0, stream>>>(GIB, eWhh + 2L*196608, ebhh + 1536,
                                            SEQ + (long)b0*512, 64,
                                            FIN + 65536 + (long)b0*512, HC, seg, BH);
      }
    }

    k_prep_dec<<<1536, 256, 0, stream>>>(dWhh, attnW, fcconW, dWih, R3);
    k_dec_init<<<512, 256, 0, stream>>>(FIN, SEQ, HB, HF, CAT, (u32*)(S + 16000));

    for (int s = 0; s < 24; ++s) {
      const int p = s & 1;
      const f16* h2in = HB + (4 + p)*32768L;
      k_gemm<<<dim3(1,4,1), 256, 0, stream>>>(h2in, 512,
          (const f16*)nullptr, attnW, 0L, 1024, 0, (const float*)nullptr, 0,
          HQ, 0L, 512, 0, 0, 0, 0, 6, 64, 64.f);
      k_score<<<256, 256, 0, stream>>>(SEQ, R3 + 2359296L, HQ, attnB, vW, S);
      k_attnctx<<<64, 256, 0, stream>>>(S, SEQ, CAT);
      k_gemm<<<dim3(1,4,1), 256, 0, stream>>>(CAT, 1024,
          R3 + 2621440L, (const float*)nullptr, 0L, 0, 0, fcconB, 0,
          INP, 0L, 512, 1, 0, 0, 0, 6, 64, 64.f);
      for (int l = 0; l < 3; ++l) {
        const f16* inp = (l == 0) ? INP : (HB + (2*(l-1) + (1-p))*32768L);
        k_cell_raw<<<8, 256, 0, stream>>>(inp,
                  dWih + (long)l*786432, R3 + (long)l*786432,
                  dbih + l*1536, dbhh + l*1536, HF + (long)l*32768,
                  HB + (2*l + p)*32768L, HB + (2*l + (1-p))*32768L,
                  (l == 2) ? CAT : (f16*)nullptr);
      }
      k_out<<<64, 256, 0, stream>>>(HF + 2*32768, fcW, fcB, OUT, s);
    }
  }
}